// Round 1
// baseline (1995.908 us; speedup 1.0000x reference)
//
#include <hip/hip_runtime.h>
#include <hip/hip_bf16.h>

// ---------------- Problem constants ----------------
#define BB     8
#define LSEQ   2048
#define MTOT   (BB*LSEQ)     // 16384
#define STIM   1024
#define HID    256
#define VOX    8192
#define DIN    512           // D_INNER
#define DST    16            // D_STATE
#define DCONV  4
#define DTR    16            // DT_RANK

// ---------------- Generic fp32 TN GEMM: C[M,N] = A[M,K] @ W[N,K]^T (+bias) --
// BM=BN=128, BK=16, 256 threads, 8x8 per thread (cols split 4+4 at stride 64
// for coalesced float4 stores).
#define GBM 128
#define GBN 128
#define GBK 16

__global__ __launch_bounds__(256) void gemm_tn(
    const float* __restrict__ A, int lda,
    const float* __restrict__ W, int ldw,
    const float* __restrict__ bias,
    float* __restrict__ C, int ldc,
    int M, int N, int K)
{
    __shared__ float As[GBK][GBM + 4];
    __shared__ float Ws[GBK][GBN + 4];

    const int tid = threadIdx.x;
    const int bm = blockIdx.y * GBM;
    const int bn = blockIdx.x * GBN;
    const int tr = tid >> 4;   // 0..15 -> rows tr*8..tr*8+7
    const int tc = tid & 15;   // 0..15 -> cols tc*4..+3 and 64+tc*4..+3

    float acc[8][8];
#pragma unroll
    for (int i = 0; i < 8; ++i)
#pragma unroll
        for (int j = 0; j < 8; ++j) acc[i][j] = 0.f;

    for (int k0 = 0; k0 < K; k0 += GBK) {
        // ---- stage tiles (each thread: 2 float4 of A, 2 float4 of W) ----
#pragma unroll
        for (int p = 0; p < 2; ++p) {
            int idx = tid + p * 256;          // 0..511
            int row = idx >> 2;               // 0..127
            int c4  = idx & 3;                // 0..3
            float4 z4 = make_float4(0.f, 0.f, 0.f, 0.f);
            int gr = bm + row;
            float4 va = (gr < M) ? *(const float4*)(A + (size_t)gr * lda + k0 + c4 * 4) : z4;
            As[c4*4+0][row] = va.x; As[c4*4+1][row] = va.y;
            As[c4*4+2][row] = va.z; As[c4*4+3][row] = va.w;
            int gn = bn + row;
            float4 vw = (gn < N) ? *(const float4*)(W + (size_t)gn * ldw + k0 + c4 * 4) : z4;
            Ws[c4*4+0][row] = vw.x; Ws[c4*4+1][row] = vw.y;
            Ws[c4*4+2][row] = vw.z; Ws[c4*4+3][row] = vw.w;
        }
        __syncthreads();

#pragma unroll
        for (int kk = 0; kk < GBK; ++kk) {
            float a[8], b[8];
#pragma unroll
            for (int i = 0; i < 8; ++i) a[i] = As[kk][tr * 8 + i];
#pragma unroll
            for (int q = 0; q < 4; ++q) {
                b[q]     = Ws[kk][tc * 4 + q];
                b[4 + q] = Ws[kk][64 + tc * 4 + q];
            }
#pragma unroll
            for (int i = 0; i < 8; ++i)
#pragma unroll
                for (int j = 0; j < 8; ++j)
                    acc[i][j] = fmaf(a[i], b[j], acc[i][j]);
        }
        __syncthreads();
    }

    // ---- epilogue: coalesced float4 stores (N is always a multiple of 4) --
#pragma unroll
    for (int i = 0; i < 8; ++i) {
        int gm = bm + tr * 8 + i;
        if (gm >= M) continue;
#pragma unroll
        for (int jj = 0; jj < 2; ++jj) {
            int gn = bn + jj * 64 + tc * 4;
            if (gn < N) {
                float4 v;
                v.x = acc[i][jj*4+0]; v.y = acc[i][jj*4+1];
                v.z = acc[i][jj*4+2]; v.w = acc[i][jj*4+3];
                if (bias) {
                    v.x += bias[gn+0]; v.y += bias[gn+1];
                    v.z += bias[gn+2]; v.w += bias[gn+3];
                }
                *(float4*)(C + (size_t)gm * ldc + gn) = v;
            }
        }
    }
}

// ---------------- conv1d (causal, depthwise, DCONV=4) + SiLU --------------
// u = xz[..., :DIN] (stride 1024). uc[b,l,d] = silu(conv_b[d] + sum_k w[d,k]*u[b,l+k-3,d])
__global__ __launch_bounds__(256) void conv_silu(
    const float* __restrict__ xz, const float* __restrict__ conv_w,
    const float* __restrict__ conv_b, float* __restrict__ uc)
{
    int idx = blockIdx.x * 256 + threadIdx.x;   // over MTOT*DIN
    int d  = idx & (DIN - 1);
    int ml = idx >> 9;                          // b*LSEQ + l
    int l  = ml & (LSEQ - 1);
    const float* base = xz + (size_t)ml * (2 * DIN) + d;
    float acc = conv_b[d];
#pragma unroll
    for (int k = 0; k < DCONV; ++k) {
        int lk = l + k - (DCONV - 1);
        if (lk >= 0) acc = fmaf(conv_w[d * DCONV + k], base[(k - (DCONV - 1)) * (2 * DIN)], acc);
    }
    float sig = 1.f / (1.f + __expf(-acc));
    uc[idx] = acc * sig;
}

// ---------------- dt projection + softplus --------------------------------
// dt[m,d] = softplus(sum_r xdb[m,r] * dt_proj_w[d,r] + dt_proj_b[d])
__global__ __launch_bounds__(256) void dtproj(
    const float* __restrict__ xdb, const float* __restrict__ w,
    const float* __restrict__ bias, float* __restrict__ dt)
{
    __shared__ float sw[DIN][DTR + 1];   // padded: coprime stride vs 32 banks
    __shared__ float sx[16][DTR + 1];
    const int tid = threadIdx.x;
    const int m0 = blockIdx.x * 16;

    for (int i = tid; i < DIN * DTR; i += 256) {
        sw[i >> 4][i & 15] = w[i];
    }
    {
        int i = tid;                     // 256 threads == 16*16 elements
        sx[i >> 4][i & 15] = xdb[(size_t)(m0 + (i >> 4)) * 48 + (i & 15)];
    }
    __syncthreads();

#pragma unroll
    for (int p = 0; p < 32; ++p) {       // 16 rows * 512 d / 256 threads
        int o = p * 256 + tid;
        int d = o & (DIN - 1);
        int row = o >> 9;
        float acc = bias[d];
#pragma unroll
        for (int k = 0; k < DTR; ++k)
            acc = fmaf(sx[row][k], sw[d][k], acc);
        // softplus
        float v = (acc > 20.f) ? acc : log1pf(__expf(acc));
        dt[(size_t)(m0 + row) * DIN + d] = v;
    }
}

// ---------------- selective scan + fused epilogue --------------------------
// lane layout: block = 256 threads = 16 channel-groups x 16 states.
// block -> (b, dchunk): d = dchunk*16 + g. State h kept in a register.
// Epilogue fused: y = (ys + uc*D) * silu(z)
#define TCH 64
__global__ __launch_bounds__(256) void scan_kernel(
    const float* __restrict__ dt,    // (MTOT, DIN)
    const float* __restrict__ xdb,   // (MTOT, 48): B at +16, C at +32
    const float* __restrict__ uc,    // (MTOT, DIN)
    const float* __restrict__ xz,    // (MTOT, 1024): z at +512
    const float* __restrict__ A_log, // (DIN, DST)
    const float* __restrict__ Dp,    // (DIN)
    float* __restrict__ y)           // (MTOT, DIN)
{
    __shared__ float s_dt[TCH][16], s_uc[TCH][16], s_B[TCH][16], s_C[TCH][16], s_y[TCH][16];

    const int tid = threadIdx.x;
    const int b   = blockIdx.x >> 5;   // 0..7
    const int dch = blockIdx.x & 31;   // 0..31
    const int g   = tid >> 4;          // channel within chunk
    const int s   = tid & 15;          // state index
    const int d   = dch * 16 + g;

    const float Av = -__expf(A_log[d * DST + s]);
    float h = 0.f;

    for (int t0 = 0; t0 < LSEQ; t0 += TCH) {
        // ---- stage TCH steps of dt/uc/B/C ----
        {
            int row = tid >> 2, q = tid & 3;
            size_t m = (size_t)(b * LSEQ + t0 + row);
            *(float4*)&s_dt[row][q*4] = *(const float4*)(dt  + m * DIN + dch * 16 + q * 4);
            *(float4*)&s_uc[row][q*4] = *(const float4*)(uc  + m * DIN + dch * 16 + q * 4);
            *(float4*)&s_B[row][q*4]  = *(const float4*)(xdb + m * 48 + 16 + q * 4);
            *(float4*)&s_C[row][q*4]  = *(const float4*)(xdb + m * 48 + 32 + q * 4);
        }
        __syncthreads();

        // ---- sequential scan over the chunk ----
#pragma unroll 4
        for (int tt = 0; tt < TCH; ++tt) {
            float dtv = s_dt[tt][g];
            float ucv = s_uc[tt][g];
            float Bv  = s_B[tt][s];
            float Cv  = s_C[tt][s];
            float dA  = __expf(dtv * Av);
            h = fmaf(dA, h, dtv * ucv * Bv);
            float p = h * Cv;
            p += __shfl_xor(p, 1);
            p += __shfl_xor(p, 2);
            p += __shfl_xor(p, 4);
            p += __shfl_xor(p, 8);
            if (s == 0) s_y[tt][g] = p;
        }
        __syncthreads();

        // ---- flush chunk with fused epilogue ----
        for (int e = tid; e < TCH * 16; e += 256) {
            int tt = e >> 4, j = e & 15;
            size_t m = (size_t)(b * LSEQ + t0 + tt);
            int dg = dch * 16 + j;
            float zv = xz[m * (2 * DIN) + DIN + dg];
            float sig = 1.f / (1.f + __expf(-zv));
            float val = (s_y[tt][j] + s_uc[tt][j] * Dp[dg]) * (zv * sig);
            y[m * DIN + dg] = val;
        }
        __syncthreads();
    }
}

// ---------------- launch ----------------------------------------------------
extern "C" void kernel_launch(void* const* d_in, const int* in_sizes, int n_in,
                              void* d_out, int out_size, void* d_ws, size_t ws_size,
                              hipStream_t stream) {
    const float* x         = (const float*)d_in[0];
    const float* proj_w    = (const float*)d_in[1];
    const float* proj_b    = (const float*)d_in[2];
    const float* in_proj_w = (const float*)d_in[3];
    const float* conv_w    = (const float*)d_in[4];
    const float* conv_b    = (const float*)d_in[5];
    const float* x_proj_w  = (const float*)d_in[6];
    const float* dt_proj_w = (const float*)d_in[7];
    const float* dt_proj_b = (const float*)d_in[8];
    const float* A_log     = (const float*)d_in[9];
    const float* Dp        = (const float*)d_in[10];
    const float* out_proj_w= (const float*)d_in[11];
    const float* head_w    = (const float*)d_in[12];
    const float* head_b    = (const float*)d_in[13];
    float* out = (float*)d_out;

    // workspace layout (floats)
    float* ws  = (float*)d_ws;
    float* h   = ws;                          // MTOT*HID
    float* xz  = h   + (size_t)MTOT * HID;    // MTOT*1024
    float* uc  = xz  + (size_t)MTOT * 1024;   // MTOT*DIN
    float* xdb = uc  + (size_t)MTOT * DIN;    // MTOT*48
    float* dtb = xdb + (size_t)MTOT * 48;     // MTOT*DIN
    float* yb  = dtb + (size_t)MTOT * DIN;    // MTOT*DIN
    float* ob  = h;                           // reuse h (dead after GEMM2): MTOT*HID

    dim3 blk(256);

    // 1) h = x @ proj_w.T + proj_b          (M=16384, N=256, K=1024)
    gemm_tn<<<dim3(HID / GBN, MTOT / GBM), blk, 0, stream>>>(
        x, STIM, proj_w, STIM, proj_b, h, HID, MTOT, HID, STIM);

    // 2) xz = h @ in_proj_w.T               (M=16384, N=1024, K=256)
    gemm_tn<<<dim3(1024 / GBN, MTOT / GBM), blk, 0, stream>>>(
        h, HID, in_proj_w, HID, nullptr, xz, 1024, MTOT, 1024, HID);

    // 3) uc = silu(conv(u))                 (u = xz[:, :512])
    conv_silu<<<(MTOT * DIN) / 256, blk, 0, stream>>>(xz, conv_w, conv_b, uc);

    // 4) xdb = uc @ x_proj_w.T              (M=16384, N=48, K=512)
    gemm_tn<<<dim3(1, MTOT / GBM), blk, 0, stream>>>(
        uc, DIN, x_proj_w, DIN, nullptr, xdb, 48, MTOT, 48, DIN);

    // 5) dt = softplus(xdb[:, :16] @ dt_proj_w.T + dt_proj_b)
    dtproj<<<MTOT / 16, blk, 0, stream>>>(xdb, dt_proj_w, dt_proj_b, dtb);

    // 6) selective scan + fused (+uc*D)*silu(z)  -> yb
    scan_kernel<<<BB * 32, blk, 0, stream>>>(dtb, xdb, uc, xz, A_log, Dp, yb);

    // 7) o = y @ out_proj_w.T               (M=16384, N=256, K=512)
    gemm_tn<<<dim3(HID / GBN, MTOT / GBM), blk, 0, stream>>>(
        yb, DIN, out_proj_w, DIN, nullptr, ob, HID, MTOT, HID, DIN);

    // 8) out = o @ head_w.T + head_b        (M=16384, N=8192, K=256)
    gemm_tn<<<dim3(VOX / GBN, MTOT / GBM), blk, 0, stream>>>(
        ob, HID, head_w, HID, head_b, out, VOX, MTOT, VOX, HID);
}

// Round 2
// 876.740 us; speedup vs baseline: 2.2765x; 2.2765x over previous
//
#include <hip/hip_runtime.h>
#include <hip/hip_bf16.h>

// ---------------- Problem constants ----------------
#define BB     8
#define LSEQ   2048
#define MTOT   (BB*LSEQ)     // 16384
#define STIM   1024
#define HID    256
#define VOX    8192
#define DIN    512           // D_INNER
#define DST    16            // D_STATE
#define DCONV  4
#define DTR    16            // DT_RANK

typedef __attribute__((ext_vector_type(8))) short bf16x8;
typedef __attribute__((ext_vector_type(4))) float f32x4;

// ---------------- async global->LDS 16B helper -----------------------------
__device__ __forceinline__ void load_lds16(const void* g, void* l) {
    __builtin_amdgcn_global_load_lds(
        (const __attribute__((address_space(1))) unsigned int*)g,
        (__attribute__((address_space(3))) unsigned int*)l, 16, 0, 0);
}

// ---------------- fp32 -> bf16 conversion ----------------------------------
__global__ __launch_bounds__(256) void cvt_bf16(
    const float* __restrict__ in, __hip_bfloat16* __restrict__ out, int n4)
{
    int i = blockIdx.x * 256 + threadIdx.x;
    if (i < n4) {
        float4 a = ((const float4*)in)[i];
        union { __hip_bfloat16 h[4]; ushort4 u; } cv;
        cv.h[0] = __float2bfloat16(a.x);
        cv.h[1] = __float2bfloat16(a.y);
        cv.h[2] = __float2bfloat16(a.z);
        cv.h[3] = __float2bfloat16(a.w);
        ((ushort4*)out)[i] = cv.u;
    }
}

// ---------------- bf16 MFMA TN GEMM: C[M,N] = A[M,K] @ W[N,K]^T (+bias) ----
// 128x128 tile, BK=32, 256 threads = 4 waves (2x2), each wave 64x64 out.
// m97 structure: global_load_lds(16B) staging, 16x16x32 bf16 MFMA.
// M,N must be multiples of 128; K multiple of 32.
template<bool BIAS, bool OUT_BF16>
__global__ __launch_bounds__(256) void gemm_bf16(
    const __hip_bfloat16* __restrict__ A, int lda,
    const __hip_bfloat16* __restrict__ W, int ldw,
    const float* __restrict__ bias,
    void* __restrict__ C, int ldc, int K)
{
    __shared__ __hip_bfloat16 As[128 * 32];
    __shared__ __hip_bfloat16 Bs[128 * 32];

    const int tid  = threadIdx.x;
    const int lane = tid & 63;
    const int wave = tid >> 6;
    const int wr = wave >> 1, wc = wave & 1;
    const int bm = blockIdx.y * 128, bn = blockIdx.x * 128;

    f32x4 acc[4][4];
#pragma unroll
    for (int i = 0; i < 4; ++i)
#pragma unroll
        for (int j = 0; j < 4; ++j) acc[i][j] = f32x4{0.f, 0.f, 0.f, 0.f};

    const int srow = tid >> 2;          // 0..63
    const int col8 = (tid & 3) * 8;

    for (int k0 = 0; k0 < K; k0 += 32) {
        // stage A,B tiles: 128x32 bf16 each; 2 x 16B loads per thread per tile
        load_lds16(A + (size_t)(bm + srow)      * lda + k0 + col8, &As[(size_t)tid * 8]);
        load_lds16(A + (size_t)(bm + 64 + srow) * lda + k0 + col8, &As[(size_t)(256 + tid) * 8]);
        load_lds16(W + (size_t)(bn + srow)      * ldw + k0 + col8, &Bs[(size_t)tid * 8]);
        load_lds16(W + (size_t)(bn + 64 + srow) * ldw + k0 + col8, &Bs[(size_t)(256 + tid) * 8]);
        __syncthreads();   // drains vmcnt before reads

        const int kk = (lane >> 4) * 8;
        bf16x8 af[4], bfr[4];
#pragma unroll
        for (int i = 0; i < 4; ++i) {
            af[i]  = *(const bf16x8*)&As[(wr * 64 + i * 16 + (lane & 15)) * 32 + kk];
            bfr[i] = *(const bf16x8*)&Bs[(wc * 64 + i * 16 + (lane & 15)) * 32 + kk];
        }
#pragma unroll
        for (int i = 0; i < 4; ++i)
#pragma unroll
            for (int j = 0; j < 4; ++j)
                acc[i][j] = __builtin_amdgcn_mfma_f32_16x16x32_bf16(af[i], bfr[j], acc[i][j], 0, 0, 0);
        __syncthreads();
    }

    // epilogue: D row = (lane>>4)*4 + r, col = lane&15  (m89-verified)
#pragma unroll
    for (int i = 0; i < 4; ++i) {
        int m = bm + wr * 64 + i * 16 + (lane >> 4) * 4;
#pragma unroll
        for (int j = 0; j < 4; ++j) {
            int n = bn + wc * 64 + j * 16 + (lane & 15);
            float bv = BIAS ? bias[n] : 0.f;
#pragma unroll
            for (int r = 0; r < 4; ++r) {
                float v = acc[i][j][r] + bv;
                if (OUT_BF16)
                    ((__hip_bfloat16*)C)[(size_t)(m + r) * ldc + n] = __float2bfloat16(v);
                else
                    ((float*)C)[(size_t)(m + r) * ldc + n] = v;
            }
        }
    }
}

// ---------------- fp32 TN GEMM (kept for the small N=48 projection) --------
#define GBM 128
#define GBN 128
#define GBK 16
__global__ __launch_bounds__(256) void gemm_tn(
    const float* __restrict__ A, int lda,
    const float* __restrict__ W, int ldw,
    const float* __restrict__ bias,
    float* __restrict__ C, int ldc,
    int M, int N, int K)
{
    __shared__ float As[GBK][GBM + 4];
    __shared__ float Ws[GBK][GBN + 4];

    const int tid = threadIdx.x;
    const int bm = blockIdx.y * GBM;
    const int bn = blockIdx.x * GBN;
    const int tr = tid >> 4;
    const int tc = tid & 15;

    float acc[8][8];
#pragma unroll
    for (int i = 0; i < 8; ++i)
#pragma unroll
        for (int j = 0; j < 8; ++j) acc[i][j] = 0.f;

    for (int k0 = 0; k0 < K; k0 += GBK) {
#pragma unroll
        for (int p = 0; p < 2; ++p) {
            int idx = tid + p * 256;
            int row = idx >> 2;
            int c4  = idx & 3;
            float4 z4 = make_float4(0.f, 0.f, 0.f, 0.f);
            int gr = bm + row;
            float4 va = (gr < M) ? *(const float4*)(A + (size_t)gr * lda + k0 + c4 * 4) : z4;
            As[c4*4+0][row] = va.x; As[c4*4+1][row] = va.y;
            As[c4*4+2][row] = va.z; As[c4*4+3][row] = va.w;
            int gn = bn + row;
            float4 vw = (gn < N) ? *(const float4*)(W + (size_t)gn * ldw + k0 + c4 * 4) : z4;
            Ws[c4*4+0][row] = vw.x; Ws[c4*4+1][row] = vw.y;
            Ws[c4*4+2][row] = vw.z; Ws[c4*4+3][row] = vw.w;
        }
        __syncthreads();

#pragma unroll
        for (int kk = 0; kk < GBK; ++kk) {
            float a[8], b[8];
#pragma unroll
            for (int i = 0; i < 8; ++i) a[i] = As[kk][tr * 8 + i];
#pragma unroll
            for (int q = 0; q < 4; ++q) {
                b[q]     = Ws[kk][tc * 4 + q];
                b[4 + q] = Ws[kk][64 + tc * 4 + q];
            }
#pragma unroll
            for (int i = 0; i < 8; ++i)
#pragma unroll
                for (int j = 0; j < 8; ++j)
                    acc[i][j] = fmaf(a[i], b[j], acc[i][j]);
        }
        __syncthreads();
    }

#pragma unroll
    for (int i = 0; i < 8; ++i) {
        int gm = bm + tr * 8 + i;
        if (gm >= M) continue;
#pragma unroll
        for (int jj = 0; jj < 2; ++jj) {
            int gn = bn + jj * 64 + tc * 4;
            if (gn < N) {
                float4 v;
                v.x = acc[i][jj*4+0]; v.y = acc[i][jj*4+1];
                v.z = acc[i][jj*4+2]; v.w = acc[i][jj*4+3];
                if (bias) {
                    v.x += bias[gn+0]; v.y += bias[gn+1];
                    v.z += bias[gn+2]; v.w += bias[gn+3];
                }
                *(float4*)(C + (size_t)gm * ldc + gn) = v;
            }
        }
    }
}

// ---------------- conv1d (causal, depthwise, DCONV=4) + SiLU ---------------
// reads xz (bf16, stride 1024), writes uc (fp32)
__global__ __launch_bounds__(256) void conv_silu(
    const __hip_bfloat16* __restrict__ xz, const float* __restrict__ conv_w,
    const float* __restrict__ conv_b, float* __restrict__ uc)
{
    int idx = blockIdx.x * 256 + threadIdx.x;   // over MTOT*DIN
    int d  = idx & (DIN - 1);
    int ml = idx >> 9;
    int l  = ml & (LSEQ - 1);
    const __hip_bfloat16* base = xz + (size_t)ml * (2 * DIN) + d;
    float acc = conv_b[d];
#pragma unroll
    for (int k = 0; k < DCONV; ++k) {
        int lk = l + k - (DCONV - 1);
        if (lk >= 0)
            acc = fmaf(conv_w[d * DCONV + k],
                       __bfloat162float(base[(k - (DCONV - 1)) * (2 * DIN)]), acc);
    }
    float sig = 1.f / (1.f + __expf(-acc));
    uc[idx] = acc * sig;
}

// ---------------- dt projection + softplus ---------------------------------
__global__ __launch_bounds__(256) void dtproj(
    const float* __restrict__ xdb, const float* __restrict__ w,
    const float* __restrict__ bias, float* __restrict__ dt)
{
    __shared__ float sw[DIN][DTR + 1];
    __shared__ float sx[16][DTR + 1];
    const int tid = threadIdx.x;
    const int m0 = blockIdx.x * 16;

    for (int i = tid; i < DIN * DTR; i += 256) {
        sw[i >> 4][i & 15] = w[i];
    }
    {
        int i = tid;
        sx[i >> 4][i & 15] = xdb[(size_t)(m0 + (i >> 4)) * 48 + (i & 15)];
    }
    __syncthreads();

#pragma unroll
    for (int p = 0; p < 32; ++p) {
        int o = p * 256 + tid;
        int d = o & (DIN - 1);
        int row = o >> 9;
        float acc = bias[d];
#pragma unroll
        for (int k = 0; k < DTR; ++k)
            acc = fmaf(sx[row][k], sw[d][k], acc);
        float v = (acc > 20.f) ? acc : log1pf(__expf(acc));
        dt[(size_t)(m0 + row) * DIN + d] = v;
    }
}

// ---------------- selective scan + fused epilogue ---------------------------
// y(bf16) = (scan + uc*D) * silu(z),  z read from bf16 xz
#define TCH 64
__global__ __launch_bounds__(256) void scan_kernel(
    const float* __restrict__ dt,    // (MTOT, DIN)
    const float* __restrict__ xdb,   // (MTOT, 48): B at +16, C at +32
    const float* __restrict__ uc,    // (MTOT, DIN)
    const __hip_bfloat16* __restrict__ xz, // (MTOT, 1024): z at +512
    const float* __restrict__ A_log, // (DIN, DST)
    const float* __restrict__ Dp,    // (DIN)
    __hip_bfloat16* __restrict__ y)  // (MTOT, DIN)
{
    __shared__ float s_dt[TCH][16], s_uc[TCH][16], s_B[TCH][16], s_C[TCH][16], s_y[TCH][16];

    const int tid = threadIdx.x;
    const int b   = blockIdx.x >> 5;
    const int dch = blockIdx.x & 31;
    const int g   = tid >> 4;
    const int s   = tid & 15;
    const int d   = dch * 16 + g;

    const float Av = -__expf(A_log[d * DST + s]);
    float h = 0.f;

    for (int t0 = 0; t0 < LSEQ; t0 += TCH) {
        {
            int row = tid >> 2, q = tid & 3;
            size_t m = (size_t)(b * LSEQ + t0 + row);
            *(float4*)&s_dt[row][q*4] = *(const float4*)(dt  + m * DIN + dch * 16 + q * 4);
            *(float4*)&s_uc[row][q*4] = *(const float4*)(uc  + m * DIN + dch * 16 + q * 4);
            *(float4*)&s_B[row][q*4]  = *(const float4*)(xdb + m * 48 + 16 + q * 4);
            *(float4*)&s_C[row][q*4]  = *(const float4*)(xdb + m * 48 + 32 + q * 4);
        }
        __syncthreads();

#pragma unroll 4
        for (int tt = 0; tt < TCH; ++tt) {
            float dtv = s_dt[tt][g];
            float ucv = s_uc[tt][g];
            float Bv  = s_B[tt][s];
            float Cv  = s_C[tt][s];
            float dA  = __expf(dtv * Av);
            h = fmaf(dA, h, dtv * ucv * Bv);
            float p = h * Cv;
            p += __shfl_xor(p, 1);
            p += __shfl_xor(p, 2);
            p += __shfl_xor(p, 4);
            p += __shfl_xor(p, 8);
            if (s == 0) s_y[tt][g] = p;
        }
        __syncthreads();

        for (int e = tid; e < TCH * 16; e += 256) {
            int tt = e >> 4, j = e & 15;
            size_t m = (size_t)(b * LSEQ + t0 + tt);
            int dg = dch * 16 + j;
            float zv = __bfloat162float(xz[m * (2 * DIN) + DIN + dg]);
            float sig = 1.f / (1.f + __expf(-zv));
            float val = (s_y[tt][j] + s_uc[tt][j] * Dp[dg]) * (zv * sig);
            y[m * DIN + dg] = __float2bfloat16(val);
        }
        __syncthreads();
    }
}

// ---------------- launch ----------------------------------------------------
extern "C" void kernel_launch(void* const* d_in, const int* in_sizes, int n_in,
                              void* d_out, int out_size, void* d_ws, size_t ws_size,
                              hipStream_t stream) {
    const float* x         = (const float*)d_in[0];
    const float* proj_w    = (const float*)d_in[1];
    const float* proj_b    = (const float*)d_in[2];
    const float* in_proj_w = (const float*)d_in[3];
    const float* conv_w    = (const float*)d_in[4];
    const float* conv_b    = (const float*)d_in[5];
    const float* x_proj_w  = (const float*)d_in[6];
    const float* dt_proj_w = (const float*)d_in[7];
    const float* dt_proj_b = (const float*)d_in[8];
    const float* A_log     = (const float*)d_in[9];
    const float* Dp        = (const float*)d_in[10];
    const float* out_proj_w= (const float*)d_in[11];
    const float* head_w    = (const float*)d_in[12];
    const float* head_b    = (const float*)d_in[13];
    float* out = (float*)d_out;

    // ---- workspace layout (bytes, all 16B aligned) ----
    char* ws = (char*)d_ws;
    __hip_bfloat16* xbf   = (__hip_bfloat16*)ws;                         ws += (size_t)MTOT * STIM * 2;   // 32MB
    __hip_bfloat16* hbf   = (__hip_bfloat16*)ws;                         ws += (size_t)MTOT * HID * 2;    // 8MB
    __hip_bfloat16* xzbf  = (__hip_bfloat16*)ws;                         ws += (size_t)MTOT * 1024 * 2;   // 32MB
    float*          uc    = (float*)ws;                                  ws += (size_t)MTOT * DIN * 4;    // 32MB
    float*          xdb   = (float*)ws;                                  ws += (size_t)MTOT * 48 * 4;     // 3MB
    float*          dtb   = (float*)ws;                                  ws += (size_t)MTOT * DIN * 4;    // 32MB
    __hip_bfloat16* ybf   = (__hip_bfloat16*)ws;                         ws += (size_t)MTOT * DIN * 2;    // 16MB
    __hip_bfloat16* obf   = (__hip_bfloat16*)ws;                         ws += (size_t)MTOT * HID * 2;    // 8MB
    __hip_bfloat16* wproj = (__hip_bfloat16*)ws;                         ws += (size_t)HID * STIM * 2;
    __hip_bfloat16* winp  = (__hip_bfloat16*)ws;                         ws += (size_t)(2*DIN) * HID * 2;
    __hip_bfloat16* wout  = (__hip_bfloat16*)ws;                         ws += (size_t)HID * DIN * 2;
    __hip_bfloat16* whead = (__hip_bfloat16*)ws;                         ws += (size_t)VOX * HID * 2;

    dim3 blk(256);

    // ---- conversions ----
    cvt_bf16<<<(MTOT * STIM / 4 + 255) / 256, blk, 0, stream>>>(x, xbf, MTOT * STIM / 4);
    cvt_bf16<<<(HID * STIM / 4 + 255) / 256, blk, 0, stream>>>(proj_w, wproj, HID * STIM / 4);
    cvt_bf16<<<(2 * DIN * HID / 4 + 255) / 256, blk, 0, stream>>>(in_proj_w, winp, 2 * DIN * HID / 4);
    cvt_bf16<<<(HID * DIN / 4 + 255) / 256, blk, 0, stream>>>(out_proj_w, wout, HID * DIN / 4);
    cvt_bf16<<<(VOX * HID / 4 + 255) / 256, blk, 0, stream>>>(head_w, whead, VOX * HID / 4);

    // 1) h = x @ proj_w.T + proj_b          (M=16384, N=256, K=1024) -> bf16
    gemm_bf16<true, true><<<dim3(HID / 128, MTOT / 128), blk, 0, stream>>>(
        xbf, STIM, wproj, STIM, proj_b, hbf, HID, STIM);

    // 2) xz = h @ in_proj_w.T               (M=16384, N=1024, K=256) -> bf16
    gemm_bf16<false, true><<<dim3(1024 / 128, MTOT / 128), blk, 0, stream>>>(
        hbf, HID, winp, HID, nullptr, xzbf, 1024, HID);

    // 3) uc = silu(conv(u))                 (u = xz[:, :512])
    conv_silu<<<(MTOT * DIN) / 256, blk, 0, stream>>>(xzbf, conv_w, conv_b, uc);

    // 4) xdb = uc @ x_proj_w.T              (M=16384, N=48, K=512)  fp32
    gemm_tn<<<dim3(1, MTOT / GBM), blk, 0, stream>>>(
        uc, DIN, x_proj_w, DIN, nullptr, xdb, 48, MTOT, 48, DIN);

    // 5) dt = softplus(xdb[:, :16] @ dt_proj_w.T + dt_proj_b)
    dtproj<<<MTOT / 16, blk, 0, stream>>>(xdb, dt_proj_w, dt_proj_b, dtb);

    // 6) selective scan + fused (+uc*D)*silu(z)  -> ybf (bf16)
    scan_kernel<<<BB * 32, blk, 0, stream>>>(dtb, xdb, uc, xzbf, A_log, Dp, ybf);

    // 7) o = y @ out_proj_w.T               (M=16384, N=256, K=512) -> bf16
    gemm_bf16<false, true><<<dim3(HID / 128, MTOT / 128), blk, 0, stream>>>(
        ybf, DIN, wout, DIN, nullptr, obf, HID, DIN);

    // 8) out = o @ head_w.T + head_b        (M=16384, N=8192, K=256) fp32 out
    gemm_bf16<true, false><<<dim3(VOX / 128, MTOT / 128), blk, 0, stream>>>(
        obf, HID, whead, HID, head_b, out, VOX, HID);
}

// Round 3
// 597.856 us; speedup vs baseline: 3.3384x; 1.4665x over previous
//
#include <hip/hip_runtime.h>
#include <hip/hip_bf16.h>

// ---------------- Problem constants ----------------
#define BB     8
#define LSEQ   2048
#define MTOT   (BB*LSEQ)     // 16384
#define STIM   1024
#define HID    256
#define VOX    8192
#define DIN    512           // D_INNER
#define DST    16            // D_STATE
#define DCONV  4
#define DTR    16            // DT_RANK
#define NCH    32            // scan chunks
#define CL     64            // chunk length (NCH*CL == LSEQ)

typedef __attribute__((ext_vector_type(8))) short bf16x8;
typedef __attribute__((ext_vector_type(4))) float f32x4;

// ---------------- async global->LDS 16B helper -----------------------------
__device__ __forceinline__ void load_lds16(const void* g, void* l) {
    __builtin_amdgcn_global_load_lds(
        (const __attribute__((address_space(1))) unsigned int*)g,
        (__attribute__((address_space(3))) unsigned int*)l, 16, 0, 0);
}

// ---------------- fp32 -> bf16 conversion ----------------------------------
__global__ __launch_bounds__(256) void cvt_bf16(
    const float* __restrict__ in, __hip_bfloat16* __restrict__ out, int n4)
{
    int i = blockIdx.x * 256 + threadIdx.x;
    if (i < n4) {
        float4 a = ((const float4*)in)[i];
        union { __hip_bfloat16 h[4]; ushort4 u; } cv;
        cv.h[0] = __float2bfloat16(a.x);
        cv.h[1] = __float2bfloat16(a.y);
        cv.h[2] = __float2bfloat16(a.z);
        cv.h[3] = __float2bfloat16(a.w);
        ((ushort4*)out)[i] = cv.u;
    }
}

// ---------------- bf16 MFMA TN GEMM: C[M,N] = A[M,K] @ W[N,K]^T (+bias) ----
template<bool BIAS, bool OUT_BF16>
__global__ __launch_bounds__(256) void gemm_bf16(
    const __hip_bfloat16* __restrict__ A, int lda,
    const __hip_bfloat16* __restrict__ W, int ldw,
    const float* __restrict__ bias,
    void* __restrict__ C, int ldc, int K)
{
    __shared__ __hip_bfloat16 As[128 * 32];
    __shared__ __hip_bfloat16 Bs[128 * 32];

    const int tid  = threadIdx.x;
    const int lane = tid & 63;
    const int wave = tid >> 6;
    const int wr = wave >> 1, wc = wave & 1;
    const int bm = blockIdx.y * 128, bn = blockIdx.x * 128;

    f32x4 acc[4][4];
#pragma unroll
    for (int i = 0; i < 4; ++i)
#pragma unroll
        for (int j = 0; j < 4; ++j) acc[i][j] = f32x4{0.f, 0.f, 0.f, 0.f};

    const int srow = tid >> 2;
    const int col8 = (tid & 3) * 8;

    for (int k0 = 0; k0 < K; k0 += 32) {
        load_lds16(A + (size_t)(bm + srow)      * lda + k0 + col8, &As[(size_t)tid * 8]);
        load_lds16(A + (size_t)(bm + 64 + srow) * lda + k0 + col8, &As[(size_t)(256 + tid) * 8]);
        load_lds16(W + (size_t)(bn + srow)      * ldw + k0 + col8, &Bs[(size_t)tid * 8]);
        load_lds16(W + (size_t)(bn + 64 + srow) * ldw + k0 + col8, &Bs[(size_t)(256 + tid) * 8]);
        __syncthreads();

        const int kk = (lane >> 4) * 8;
        bf16x8 af[4], bfr[4];
#pragma unroll
        for (int i = 0; i < 4; ++i) {
            af[i]  = *(const bf16x8*)&As[(wr * 64 + i * 16 + (lane & 15)) * 32 + kk];
            bfr[i] = *(const bf16x8*)&Bs[(wc * 64 + i * 16 + (lane & 15)) * 32 + kk];
        }
#pragma unroll
        for (int i = 0; i < 4; ++i)
#pragma unroll
            for (int j = 0; j < 4; ++j)
                acc[i][j] = __builtin_amdgcn_mfma_f32_16x16x32_bf16(af[i], bfr[j], acc[i][j], 0, 0, 0);
        __syncthreads();
    }

#pragma unroll
    for (int i = 0; i < 4; ++i) {
        int m = bm + wr * 64 + i * 16 + (lane >> 4) * 4;
#pragma unroll
        for (int j = 0; j < 4; ++j) {
            int n = bn + wc * 64 + j * 16 + (lane & 15);
            float bv = BIAS ? bias[n] : 0.f;
#pragma unroll
            for (int r = 0; r < 4; ++r) {
                float v = acc[i][j][r] + bv;
                if (OUT_BF16)
                    ((__hip_bfloat16*)C)[(size_t)(m + r) * ldc + n] = __float2bfloat16(v);
                else
                    ((float*)C)[(size_t)(m + r) * ldc + n] = v;
            }
        }
    }
}

// ---------------- fp32 TN GEMM (small N=48 projection) ---------------------
#define GBM 128
#define GBN 128
#define GBK 16
__global__ __launch_bounds__(256) void gemm_tn(
    const float* __restrict__ A, int lda,
    const float* __restrict__ W, int ldw,
    const float* __restrict__ bias,
    float* __restrict__ C, int ldc,
    int M, int N, int K)
{
    __shared__ float As[GBK][GBM + 4];
    __shared__ float Ws[GBK][GBN + 4];

    const int tid = threadIdx.x;
    const int bm = blockIdx.y * GBM;
    const int bn = blockIdx.x * GBN;
    const int tr = tid >> 4;
    const int tc = tid & 15;

    float acc[8][8];
#pragma unroll
    for (int i = 0; i < 8; ++i)
#pragma unroll
        for (int j = 0; j < 8; ++j) acc[i][j] = 0.f;

    for (int k0 = 0; k0 < K; k0 += GBK) {
#pragma unroll
        for (int p = 0; p < 2; ++p) {
            int idx = tid + p * 256;
            int row = idx >> 2;
            int c4  = idx & 3;
            float4 z4 = make_float4(0.f, 0.f, 0.f, 0.f);
            int gr = bm + row;
            float4 va = (gr < M) ? *(const float4*)(A + (size_t)gr * lda + k0 + c4 * 4) : z4;
            As[c4*4+0][row] = va.x; As[c4*4+1][row] = va.y;
            As[c4*4+2][row] = va.z; As[c4*4+3][row] = va.w;
            int gn = bn + row;
            float4 vw = (gn < N) ? *(const float4*)(W + (size_t)gn * ldw + k0 + c4 * 4) : z4;
            Ws[c4*4+0][row] = vw.x; Ws[c4*4+1][row] = vw.y;
            Ws[c4*4+2][row] = vw.z; Ws[c4*4+3][row] = vw.w;
        }
        __syncthreads();

#pragma unroll
        for (int kk = 0; kk < GBK; ++kk) {
            float a[8], b[8];
#pragma unroll
            for (int i = 0; i < 8; ++i) a[i] = As[kk][tr * 8 + i];
#pragma unroll
            for (int q = 0; q < 4; ++q) {
                b[q]     = Ws[kk][tc * 4 + q];
                b[4 + q] = Ws[kk][64 + tc * 4 + q];
            }
#pragma unroll
            for (int i = 0; i < 8; ++i)
#pragma unroll
                for (int j = 0; j < 8; ++j)
                    acc[i][j] = fmaf(a[i], b[j], acc[i][j]);
        }
        __syncthreads();
    }

#pragma unroll
    for (int i = 0; i < 8; ++i) {
        int gm = bm + tr * 8 + i;
        if (gm >= M) continue;
#pragma unroll
        for (int jj = 0; jj < 2; ++jj) {
            int gn = bn + jj * 64 + tc * 4;
            if (gn < N) {
                float4 v;
                v.x = acc[i][jj*4+0]; v.y = acc[i][jj*4+1];
                v.z = acc[i][jj*4+2]; v.w = acc[i][jj*4+3];
                if (bias) {
                    v.x += bias[gn+0]; v.y += bias[gn+1];
                    v.z += bias[gn+2]; v.w += bias[gn+3];
                }
                *(float4*)(C + (size_t)gm * ldc + gn) = v;
            }
        }
    }
}

// ---------------- conv1d (causal, depthwise, DCONV=4) + SiLU ---------------
__global__ __launch_bounds__(256) void conv_silu(
    const __hip_bfloat16* __restrict__ xz, const float* __restrict__ conv_w,
    const float* __restrict__ conv_b, float* __restrict__ uc)
{
    int idx = blockIdx.x * 256 + threadIdx.x;   // over MTOT*DIN
    int d  = idx & (DIN - 1);
    int ml = idx >> 9;
    int l  = ml & (LSEQ - 1);
    const __hip_bfloat16* base = xz + (size_t)ml * (2 * DIN) + d;
    float acc = conv_b[d];
#pragma unroll
    for (int k = 0; k < DCONV; ++k) {
        int lk = l + k - (DCONV - 1);
        if (lk >= 0)
            acc = fmaf(conv_w[d * DCONV + k],
                       __bfloat162float(base[(k - (DCONV - 1)) * (2 * DIN)]), acc);
    }
    float sig = 1.f / (1.f + __expf(-acc));
    uc[idx] = acc * sig;
}

// ---------------- dt projection + softplus ---------------------------------
__global__ __launch_bounds__(256) void dtproj(
    const float* __restrict__ xdb, const float* __restrict__ w,
    const float* __restrict__ bias, float* __restrict__ dt)
{
    __shared__ float sw[DIN][DTR + 1];
    __shared__ float sx[16][DTR + 1];
    const int tid = threadIdx.x;
    const int m0 = blockIdx.x * 16;

    for (int i = tid; i < DIN * DTR; i += 256) {
        sw[i >> 4][i & 15] = w[i];
    }
    {
        int i = tid;
        sx[i >> 4][i & 15] = xdb[(size_t)(m0 + (i >> 4)) * 48 + (i & 15)];
    }
    __syncthreads();

#pragma unroll
    for (int p = 0; p < 32; ++p) {
        int o = p * 256 + tid;
        int d = o & (DIN - 1);
        int row = o >> 9;
        float acc = bias[d];
#pragma unroll
        for (int k = 0; k < DTR; ++k)
            acc = fmaf(sx[row][k], sw[d][k], acc);
        float v = (acc > 20.f) ? acc : log1pf(__expf(acc));
        dt[(size_t)(m0 + row) * DIN + d] = v;
    }
}

// ---------------- chunked selective scan ------------------------------------
// h_t = exp(dt_t*Av)*h_{t-1} + dt_t*uc_t*B_t ; y_t = sum_s h_t*C_t
// Pass1: per chunk, compute P = exp(Av*sum dt) and S = chunk-end h from 0.
// Pass2: combine chunk states sequentially (32 steps).
// Pass3: replay each chunk from its h_start, emit y with fused epilogue.
// Block layout for pass1/3: (b, chunk c, dch) ; 256 thr = 16 d x 16 s.

__global__ __launch_bounds__(256) void scan_pass1(
    const float* __restrict__ dt, const float* __restrict__ xdb,
    const float* __restrict__ uc, const float* __restrict__ A_log,
    float* __restrict__ midP, float* __restrict__ midS)
{
    __shared__ float s_dt[CL][16], s_uc[CL][16], s_B[CL][16];
    const int tid = threadIdx.x;
    const int blk = blockIdx.x;        // (b*NCH + c)*32 + dch
    const int dch = blk & 31;
    const int bc  = blk >> 5;          // b*NCH + c
    const int g = tid >> 4, s = tid & 15;
    const int d = dch * 16 + g;
    const float Av = -__expf(A_log[d * DST + s]);

    {
        int row = tid >> 2, q = tid & 3;
        size_t m = (size_t)bc * CL + row;        // == b*LSEQ + c*CL + row
        *(float4*)&s_dt[row][q*4] = *(const float4*)(dt  + m * DIN + dch * 16 + q * 4);
        *(float4*)&s_uc[row][q*4] = *(const float4*)(uc  + m * DIN + dch * 16 + q * 4);
        *(float4*)&s_B[row][q*4]  = *(const float4*)(xdb + m * 48 + 16 + q * 4);
    }
    __syncthreads();

    float h = 0.f, sdt = 0.f;
#pragma unroll 8
    for (int tt = 0; tt < CL; ++tt) {
        float dtv = s_dt[tt][g];
        float dA  = __expf(dtv * Av);
        h = fmaf(dA, h, dtv * s_uc[tt][g] * s_B[tt][s]);
        sdt += dtv;
    }
    size_t o = (size_t)blk * 256 + tid;   // ((b*NCH+c)*DIN + d)*DST + s
    midP[o] = __expf(sdt * Av);
    midS[o] = h;
}

__global__ __launch_bounds__(256) void scan_pass2(
    const float* __restrict__ midP, const float* __restrict__ midS,
    float* __restrict__ hstart)
{
    int t = blockIdx.x * 256 + threadIdx.x;   // (b*DIN+d)*DST+s, 65536 total
    int b  = t >> 13;
    int ds = t & 8191;
    float h = 0.f;
#pragma unroll
    for (int c = 0; c < NCH; ++c) {
        size_t o = ((size_t)(b * NCH + c) << 13) + ds;
        hstart[o] = h;
        h = fmaf(midP[o], h, midS[o]);
    }
}

__global__ __launch_bounds__(256) void scan_pass3(
    const float* __restrict__ dt, const float* __restrict__ xdb,
    const float* __restrict__ uc, const __hip_bfloat16* __restrict__ xz,
    const float* __restrict__ A_log, const float* __restrict__ Dp,
    const float* __restrict__ hstart, __hip_bfloat16* __restrict__ y)
{
    __shared__ float s_dt[CL][16], s_uc[CL][16], s_B[CL][16], s_C[CL][16], s_y[CL][16];
    const int tid = threadIdx.x;
    const int blk = blockIdx.x;
    const int dch = blk & 31;
    const int bc  = blk >> 5;
    const int g = tid >> 4, s = tid & 15;
    const int d = dch * 16 + g;
    const float Av = -__expf(A_log[d * DST + s]);

    {
        int row = tid >> 2, q = tid & 3;
        size_t m = (size_t)bc * CL + row;
        *(float4*)&s_dt[row][q*4] = *(const float4*)(dt  + m * DIN + dch * 16 + q * 4);
        *(float4*)&s_uc[row][q*4] = *(const float4*)(uc  + m * DIN + dch * 16 + q * 4);
        *(float4*)&s_B[row][q*4]  = *(const float4*)(xdb + m * 48 + 16 + q * 4);
        *(float4*)&s_C[row][q*4]  = *(const float4*)(xdb + m * 48 + 32 + q * 4);
    }
    float h = hstart[(size_t)blk * 256 + tid];
    __syncthreads();

#pragma unroll 4
    for (int tt = 0; tt < CL; ++tt) {
        float dtv = s_dt[tt][g];
        float dA  = __expf(dtv * Av);
        h = fmaf(dA, h, dtv * s_uc[tt][g] * s_B[tt][s]);
        float p = h * s_C[tt][s];
        p += __shfl_xor(p, 1);
        p += __shfl_xor(p, 2);
        p += __shfl_xor(p, 4);
        p += __shfl_xor(p, 8);
        if (s == 0) s_y[tt][g] = p;
    }
    __syncthreads();

    for (int e = tid; e < CL * 16; e += 256) {
        int tt = e >> 4, j = e & 15;
        size_t m = (size_t)bc * CL + tt;
        int dg = dch * 16 + j;
        float zv = __bfloat162float(xz[m * 1024 + 512 + dg]);
        float sig = 1.f / (1.f + __expf(-zv));
        float val = (s_y[tt][j] + s_uc[tt][j] * Dp[dg]) * (zv * sig);
        y[m * DIN + dg] = __float2bfloat16(val);
    }
}

// ---------------- launch ----------------------------------------------------
extern "C" void kernel_launch(void* const* d_in, const int* in_sizes, int n_in,
                              void* d_out, int out_size, void* d_ws, size_t ws_size,
                              hipStream_t stream) {
    const float* x         = (const float*)d_in[0];
    const float* proj_w    = (const float*)d_in[1];
    const float* proj_b    = (const float*)d_in[2];
    const float* in_proj_w = (const float*)d_in[3];
    const float* conv_w    = (const float*)d_in[4];
    const float* conv_b    = (const float*)d_in[5];
    const float* x_proj_w  = (const float*)d_in[6];
    const float* dt_proj_w = (const float*)d_in[7];
    const float* dt_proj_b = (const float*)d_in[8];
    const float* A_log     = (const float*)d_in[9];
    const float* Dp        = (const float*)d_in[10];
    const float* out_proj_w= (const float*)d_in[11];
    const float* head_w    = (const float*)d_in[12];
    const float* head_b    = (const float*)d_in[13];
    float* out = (float*)d_out;

    // ---- workspace layout ----
    char* ws = (char*)d_ws;
    __hip_bfloat16* xbf   = (__hip_bfloat16*)ws;  ws += (size_t)MTOT * STIM * 2;   // 32MB (dead after gemm1)
    __hip_bfloat16* hbf   = (__hip_bfloat16*)ws;  ws += (size_t)MTOT * HID * 2;
    __hip_bfloat16* xzbf  = (__hip_bfloat16*)ws;  ws += (size_t)MTOT * 1024 * 2;
    float*          uc    = (float*)ws;           ws += (size_t)MTOT * DIN * 4;
    float*          xdb   = (float*)ws;           ws += (size_t)MTOT * 48 * 4;
    float*          dtb   = (float*)ws;           ws += (size_t)MTOT * DIN * 4;
    __hip_bfloat16* ybf   = (__hip_bfloat16*)ws;  ws += (size_t)MTOT * DIN * 2;
    __hip_bfloat16* obf   = (__hip_bfloat16*)ws;  ws += (size_t)MTOT * HID * 2;
    __hip_bfloat16* wproj = (__hip_bfloat16*)ws;  ws += (size_t)HID * STIM * 2;
    __hip_bfloat16* winp  = (__hip_bfloat16*)ws;  ws += (size_t)(2*DIN) * HID * 2;
    __hip_bfloat16* wout  = (__hip_bfloat16*)ws;  ws += (size_t)HID * DIN * 2;
    __hip_bfloat16* whead = (__hip_bfloat16*)ws;  ws += (size_t)VOX * HID * 2;

    // scan scratch aliases xbf (dead after gemm1): 3 x 8MB <= 32MB
    float* midP   = (float*)xbf;
    float* midS   = midP + (size_t)BB * NCH * DIN * DST;
    float* hstart = midS + (size_t)BB * NCH * DIN * DST;

    dim3 blk(256);

    // ---- conversions ----
    cvt_bf16<<<(MTOT * STIM / 4 + 255) / 256, blk, 0, stream>>>(x, xbf, MTOT * STIM / 4);
    cvt_bf16<<<(HID * STIM / 4 + 255) / 256, blk, 0, stream>>>(proj_w, wproj, HID * STIM / 4);
    cvt_bf16<<<(2 * DIN * HID / 4 + 255) / 256, blk, 0, stream>>>(in_proj_w, winp, 2 * DIN * HID / 4);
    cvt_bf16<<<(HID * DIN / 4 + 255) / 256, blk, 0, stream>>>(out_proj_w, wout, HID * DIN / 4);
    cvt_bf16<<<(VOX * HID / 4 + 255) / 256, blk, 0, stream>>>(head_w, whead, VOX * HID / 4);

    // 1) h = x @ proj_w.T + proj_b          (M=16384, N=256, K=1024) -> bf16
    gemm_bf16<true, true><<<dim3(HID / 128, MTOT / 128), blk, 0, stream>>>(
        xbf, STIM, wproj, STIM, proj_b, hbf, HID, STIM);

    // 2) xz = h @ in_proj_w.T               (M=16384, N=1024, K=256) -> bf16
    gemm_bf16<false, true><<<dim3(1024 / 128, MTOT / 128), blk, 0, stream>>>(
        hbf, HID, winp, HID, nullptr, xzbf, 1024, HID);

    // 3) uc = silu(conv(u))                 (u = xz[:, :512])
    conv_silu<<<(MTOT * DIN) / 256, blk, 0, stream>>>(xzbf, conv_w, conv_b, uc);

    // 4) xdb = uc @ x_proj_w.T              (M=16384, N=48, K=512)  fp32
    gemm_tn<<<dim3(1, MTOT / GBM), blk, 0, stream>>>(
        uc, DIN, x_proj_w, DIN, nullptr, xdb, 48, MTOT, 48, DIN);

    // 5) dt = softplus(xdb[:, :16] @ dt_proj_w.T + dt_proj_b)
    dtproj<<<MTOT / 16, blk, 0, stream>>>(xdb, dt_proj_w, dt_proj_b, dtb);

    // 6) chunked selective scan + fused epilogue -> ybf (bf16)
    scan_pass1<<<BB * NCH * 32, blk, 0, stream>>>(dtb, xdb, uc, A_log, midP, midS);
    scan_pass2<<<BB * DIN * DST / 256, blk, 0, stream>>>(midP, midS, hstart);
    scan_pass3<<<BB * NCH * 32, blk, 0, stream>>>(dtb, xdb, uc, xzbf, A_log, Dp, hstart, ybf);

    // 7) o = y @ out_proj_w.T               (M=16384, N=256, K=512) -> bf16
    gemm_bf16<false, true><<<dim3(HID / 128, MTOT / 128), blk, 0, stream>>>(
        ybf, DIN, wout, DIN, nullptr, obf, HID, DIN);

    // 8) out = o @ head_w.T + head_b        (M=16384, N=8192, K=256) fp32 out
    gemm_bf16<true, false><<<dim3(VOX / 128, MTOT / 128), blk, 0, stream>>>(
        obf, HID, whead, HID, head_b, out, VOX, HID);
}

// Round 5
// 552.178 us; speedup vs baseline: 3.6146x; 1.0827x over previous
//
#include <hip/hip_runtime.h>
#include <hip/hip_bf16.h>

// ---------------- Problem constants ----------------
#define BB     8
#define LSEQ   2048
#define MTOT   (BB*LSEQ)     // 16384
#define STIM   1024
#define HID    256
#define VOX    8192
#define DIN    512           // D_INNER
#define DST    16            // D_STATE
#define DCONV  4
#define DTR    16            // DT_RANK
#define NCH    32            // scan chunks
#define CL     64            // chunk length (NCH*CL == LSEQ)

typedef __attribute__((ext_vector_type(8))) short bf16x8;
typedef __attribute__((ext_vector_type(4))) float f32x4;

// ---------------- async global->LDS 16B helper -----------------------------
__device__ __forceinline__ void load_lds16(const void* g, void* l) {
    __builtin_amdgcn_global_load_lds(
        (const __attribute__((address_space(1))) unsigned int*)g,
        (__attribute__((address_space(3))) unsigned int*)l, 16, 0, 0);
}

// ---------------- fp32 -> bf16 conversion ----------------------------------
__global__ __launch_bounds__(256) void cvt_bf16(
    const float* __restrict__ in, __hip_bfloat16* __restrict__ out, int n4)
{
    int i = blockIdx.x * 256 + threadIdx.x;
    if (i < n4) {
        float4 a = ((const float4*)in)[i];
        union { __hip_bfloat16 h[4]; ushort4 u; } cv;
        cv.h[0] = __float2bfloat16(a.x);
        cv.h[1] = __float2bfloat16(a.y);
        cv.h[2] = __float2bfloat16(a.z);
        cv.h[3] = __float2bfloat16(a.w);
        ((ushort4*)out)[i] = cv.u;
    }
}

// ---- x_proj_w (48x512) -> zero-padded bf16 (64x512) -----------------------
__global__ __launch_bounds__(256) void cvt_pad_xproj(
    const float* __restrict__ in, __hip_bfloat16* __restrict__ out)
{
    int i = blockIdx.x * 256 + threadIdx.x;   // 64*512
    int row = i >> 9;
    out[i] = (row < 48) ? __float2bfloat16(in[(i & 511) | (row << 9)]) : __float2bfloat16(0.f);
}

// ---------------- bf16 MFMA TN GEMM: C[M,N] = A[M,K] @ W[N,K]^T (+bias) ----
// 128x128 tile, BK=32, 256 threads = 4 waves (2x2), each wave 64x64 out.
template<bool BIAS, bool OUT_BF16, bool SWZ>
__global__ __launch_bounds__(256) void gemm_bf16(
    const __hip_bfloat16* __restrict__ A, int lda,
    const __hip_bfloat16* __restrict__ W, int ldw,
    const float* __restrict__ bias,
    void* __restrict__ C, int ldc, int K)
{
    __shared__ __hip_bfloat16 As[128 * 32];
    __shared__ __hip_bfloat16 Bs[128 * 32];

    const int tid  = threadIdx.x;
    const int lane = tid & 63;
    const int wave = tid >> 6;
    const int wr = wave >> 1, wc = wave & 1;

    int bx = blockIdx.x, by = blockIdx.y;
    if (SWZ) {
        int nwg = gridDim.x * gridDim.y;
        int wg  = by * gridDim.x + bx;
        wg = (wg & 7) * (nwg >> 3) + (wg >> 3);   // bijective: nwg % 8 == 0
        bx = wg % gridDim.x;
        by = wg / gridDim.x;
    }
    const int bm = by * 128, bn = bx * 128;

    f32x4 acc[4][4];
#pragma unroll
    for (int i = 0; i < 4; ++i)
#pragma unroll
        for (int j = 0; j < 4; ++j) acc[i][j] = f32x4{0.f, 0.f, 0.f, 0.f};

    const int srow = tid >> 2;
    const int col8 = (tid & 3) * 8;

    for (int k0 = 0; k0 < K; k0 += 32) {
        load_lds16(A + (size_t)(bm + srow)      * lda + k0 + col8, &As[(size_t)tid * 8]);
        load_lds16(A + (size_t)(bm + 64 + srow) * lda + k0 + col8, &As[(size_t)(256 + tid) * 8]);
        load_lds16(W + (size_t)(bn + srow)      * ldw + k0 + col8, &Bs[(size_t)tid * 8]);
        load_lds16(W + (size_t)(bn + 64 + srow) * ldw + k0 + col8, &Bs[(size_t)(256 + tid) * 8]);
        __syncthreads();

        const int kk = (lane >> 4) * 8;
        bf16x8 af[4], bfr[4];
#pragma unroll
        for (int i = 0; i < 4; ++i) {
            af[i]  = *(const bf16x8*)&As[(wr * 64 + i * 16 + (lane & 15)) * 32 + kk];
            bfr[i] = *(const bf16x8*)&Bs[(wc * 64 + i * 16 + (lane & 15)) * 32 + kk];
        }
#pragma unroll
        for (int i = 0; i < 4; ++i)
#pragma unroll
            for (int j = 0; j < 4; ++j)
                acc[i][j] = __builtin_amdgcn_mfma_f32_16x16x32_bf16(af[i], bfr[j], acc[i][j], 0, 0, 0);
        __syncthreads();
    }

#pragma unroll
    for (int i = 0; i < 4; ++i) {
        int m = bm + wr * 64 + i * 16 + (lane >> 4) * 4;
#pragma unroll
        for (int j = 0; j < 4; ++j) {
            int n = bn + wc * 64 + j * 16 + (lane & 15);
            float bv = BIAS ? bias[n] : 0.f;
#pragma unroll
            for (int r = 0; r < 4; ++r) {
                float v = acc[i][j][r] + bv;
                if (OUT_BF16)
                    ((__hip_bfloat16*)C)[(size_t)(m + r) * ldc + n] = __float2bfloat16(v);
                else
                    ((float*)C)[(size_t)(m + r) * ldc + n] = v;
            }
        }
    }
}

// ---------------- xdb = ucb @ wxpad^T  (M=16384, N=48 of 64, K=512) --------
// 64x64 tile, 4 waves (2x2) of 32x32, masked fp32 store n<48.
__global__ __launch_bounds__(256) void gemm_xdb(
    const __hip_bfloat16* __restrict__ A,    // ucb (MTOT,512)
    const __hip_bfloat16* __restrict__ W,    // wxpad (64,512)
    float* __restrict__ C)                   // xdb (MTOT,48)
{
    __shared__ __hip_bfloat16 As[64 * 32];
    __shared__ __hip_bfloat16 Bs[64 * 32];

    const int tid  = threadIdx.x;
    const int lane = tid & 63;
    const int wave = tid >> 6;
    const int wr = wave >> 1, wc = wave & 1;
    const int bm = blockIdx.x * 64;

    f32x4 acc[2][2];
#pragma unroll
    for (int i = 0; i < 2; ++i)
#pragma unroll
        for (int j = 0; j < 2; ++j) acc[i][j] = f32x4{0.f, 0.f, 0.f, 0.f};

    const int srow = tid >> 2;
    const int col8 = (tid & 3) * 8;

    for (int k0 = 0; k0 < DIN; k0 += 32) {
        load_lds16(A + (size_t)(bm + srow) * DIN + k0 + col8, &As[(size_t)tid * 8]);
        load_lds16(W + (size_t)srow * DIN + k0 + col8, &Bs[(size_t)tid * 8]);
        __syncthreads();

        const int kk = (lane >> 4) * 8;
        bf16x8 af[2], bfr[2];
#pragma unroll
        for (int i = 0; i < 2; ++i) {
            af[i]  = *(const bf16x8*)&As[(wr * 32 + i * 16 + (lane & 15)) * 32 + kk];
            bfr[i] = *(const bf16x8*)&Bs[(wc * 32 + i * 16 + (lane & 15)) * 32 + kk];
        }
#pragma unroll
        for (int i = 0; i < 2; ++i)
#pragma unroll
            for (int j = 0; j < 2; ++j)
                acc[i][j] = __builtin_amdgcn_mfma_f32_16x16x32_bf16(af[i], bfr[j], acc[i][j], 0, 0, 0);
        __syncthreads();
    }

#pragma unroll
    for (int i = 0; i < 2; ++i) {
        int m = bm + wr * 32 + i * 16 + (lane >> 4) * 4;
#pragma unroll
        for (int j = 0; j < 2; ++j) {
            int n = wc * 32 + j * 16 + (lane & 15);
            if (n < 48) {
#pragma unroll
                for (int r = 0; r < 4; ++r)
                    C[(size_t)(m + r) * 48 + n] = acc[i][j][r];
            }
        }
    }
}

// ---------------- conv1d + SiLU -> uc (fp32) + ucb (bf16) ------------------
// vectorized: each thread handles 8 channels of one row. (R4 bug fixed:
// results staged in vout[8], no stray writes.)
__global__ __launch_bounds__(256) void conv_silu(
    const __hip_bfloat16* __restrict__ xz, const float* __restrict__ conv_w,
    const float* __restrict__ conv_b, float* __restrict__ uc,
    __hip_bfloat16* __restrict__ ucb)
{
    int idx = blockIdx.x * 256 + threadIdx.x;   // over MTOT*DIN/8
    int d8  = (idx & 63) * 8;
    int m   = idx >> 6;
    int l   = m & (LSEQ - 1);

    float4 w4[8];
#pragma unroll
    for (int j = 0; j < 8; ++j) w4[j] = *(const float4*)(conv_w + (d8 + j) * 4);

    float acc[8];
    {
        float4 b0 = *(const float4*)(conv_b + d8);
        float4 b1 = *(const float4*)(conv_b + d8 + 4);
        acc[0]=b0.x; acc[1]=b0.y; acc[2]=b0.z; acc[3]=b0.w;
        acc[4]=b1.x; acc[5]=b1.y; acc[6]=b1.z; acc[7]=b1.w;
    }
#pragma unroll
    for (int k = 0; k < DCONV; ++k) {
        int lk = l + k - (DCONV - 1);
        if (lk >= 0) {
            bf16x8 v = *(const bf16x8*)(xz + (size_t)(m + k - (DCONV - 1)) * 1024 + d8);
#pragma unroll
            for (int j = 0; j < 8; ++j) {
                float w = (k == 0) ? w4[j].x : (k == 1) ? w4[j].y : (k == 2) ? w4[j].z : w4[j].w;
                union { short s; __hip_bfloat16 h; } cv; cv.s = v[j];
                acc[j] = fmaf(w, __bfloat162float(cv.h), acc[j]);
            }
        }
    }

    float vout[8];
    bf16x8 ob;
#pragma unroll
    for (int j = 0; j < 8; ++j) {
        float sig = 1.f / (1.f + __expf(-acc[j]));
        float v = acc[j] * sig;
        vout[j] = v;
        union { __hip_bfloat16 h; short s; } cv; cv.h = __float2bfloat16(v);
        ob[j] = cv.s;
    }
    *(float4*)(uc + (size_t)m * DIN + d8)     = *(float4*)&vout[0];
    *(float4*)(uc + (size_t)m * DIN + d8 + 4) = *(float4*)&vout[4];
    *(bf16x8*)(ucb + (size_t)m * DIN + d8)    = ob;
}

// ---------------- chunked selective scan (dt fused in-kernel) ---------------
// dt[m,d] = softplus(xdb[m,:16] @ dt_proj_w[d,:] + dt_proj_b[d])
// h_t = exp(dt*Av)*h + dt*uc*B ; y = sum_s h*C
__global__ __launch_bounds__(256) void scan_pass1(
    const float* __restrict__ xdb, const float* __restrict__ uc,
    const float* __restrict__ dtw, const float* __restrict__ dtbias,
    const float* __restrict__ A_log,
    float* __restrict__ midP, float* __restrict__ midS)
{
    __shared__ float s_dt[CL][16], s_uc[CL][16], s_B[CL][16], s_xt[CL][16];
    __shared__ float s_w[16][17];
    __shared__ float s_bias[16];
    const int tid = threadIdx.x;
    const int blk = blockIdx.x;        // (b*NCH + c)*32 + dch
    const int dch = blk & 31;
    const int bc  = blk >> 5;
    const int g = tid >> 4, s = tid & 15;
    const int d = dch * 16 + g;
    const float Av = -__expf(A_log[d * DST + s]);

    {
        int row = tid >> 2, q = tid & 3;
        size_t m = (size_t)bc * CL + row;
        *(float4*)&s_uc[row][q*4] = *(const float4*)(uc  + m * DIN + dch * 16 + q * 4);
        *(float4*)&s_B[row][q*4]  = *(const float4*)(xdb + m * 48 + 16 + q * 4);
        *(float4*)&s_xt[row][q*4] = *(const float4*)(xdb + m * 48 + q * 4);
        s_w[tid >> 4][tid & 15] = dtw[(dch * 16 + (tid >> 4)) * DTR + (tid & 15)];
        if (tid < 16) s_bias[tid] = dtbias[dch * 16 + tid];
    }
    __syncthreads();

    // compute dt for 64 rows x 16 channels
#pragma unroll
    for (int p = 0; p < 4; ++p) {
        int e = p * 256 + tid;
        int tt = e >> 4, gg = e & 15;
        float a = s_bias[gg];
#pragma unroll
        for (int r = 0; r < DTR; ++r)
            a = fmaf(s_xt[tt][r], s_w[gg][r], a);
        s_dt[tt][gg] = (a > 20.f) ? a : log1pf(__expf(a));
    }
    __syncthreads();

    float h = 0.f, sdt = 0.f;
#pragma unroll 8
    for (int tt = 0; tt < CL; ++tt) {
        float dtv = s_dt[tt][g];
        float dA  = __expf(dtv * Av);
        h = fmaf(dA, h, dtv * s_uc[tt][g] * s_B[tt][s]);
        sdt += dtv;
    }
    size_t o = (size_t)blk * 256 + tid;
    midP[o] = __expf(sdt * Av);
    midS[o] = h;
}

__global__ __launch_bounds__(256) void scan_pass2(
    const float* __restrict__ midP, const float* __restrict__ midS,
    float* __restrict__ hstart)
{
    int t = blockIdx.x * 256 + threadIdx.x;
    int b  = t >> 13;
    int ds = t & 8191;
    float h = 0.f;
#pragma unroll
    for (int c = 0; c < NCH; ++c) {
        size_t o = ((size_t)(b * NCH + c) << 13) + ds;
        hstart[o] = h;
        h = fmaf(midP[o], h, midS[o]);
    }
}

__global__ __launch_bounds__(256) void scan_pass3(
    const float* __restrict__ xdb, const float* __restrict__ uc,
    const float* __restrict__ dtw, const float* __restrict__ dtbias,
    const __hip_bfloat16* __restrict__ xz,
    const float* __restrict__ A_log, const float* __restrict__ Dp,
    const float* __restrict__ hstart, __hip_bfloat16* __restrict__ y)
{
    __shared__ float s_dt[CL][16], s_uc[CL][16], s_B[CL][16], s_C[CL][16], s_xt[CL][16], s_y[CL][16];
    __shared__ float s_w[16][17];
    __shared__ float s_bias[16];
    const int tid = threadIdx.x;
    const int blk = blockIdx.x;
    const int dch = blk & 31;
    const int bc  = blk >> 5;
    const int g = tid >> 4, s = tid & 15;
    const int d = dch * 16 + g;
    const float Av = -__expf(A_log[d * DST + s]);

    {
        int row = tid >> 2, q = tid & 3;
        size_t m = (size_t)bc * CL + row;
        *(float4*)&s_uc[row][q*4] = *(const float4*)(uc  + m * DIN + dch * 16 + q * 4);
        *(float4*)&s_B[row][q*4]  = *(const float4*)(xdb + m * 48 + 16 + q * 4);
        *(float4*)&s_C[row][q*4]  = *(const float4*)(xdb + m * 48 + 32 + q * 4);
        *(float4*)&s_xt[row][q*4] = *(const float4*)(xdb + m * 48 + q * 4);
        s_w[tid >> 4][tid & 15] = dtw[(dch * 16 + (tid >> 4)) * DTR + (tid & 15)];
        if (tid < 16) s_bias[tid] = dtbias[dch * 16 + tid];
    }
    float h = hstart[(size_t)blk * 256 + tid];
    __syncthreads();

#pragma unroll
    for (int p = 0; p < 4; ++p) {
        int e = p * 256 + tid;
        int tt = e >> 4, gg = e & 15;
        float a = s_bias[gg];
#pragma unroll
        for (int r = 0; r < DTR; ++r)
            a = fmaf(s_xt[tt][r], s_w[gg][r], a);
        s_dt[tt][gg] = (a > 20.f) ? a : log1pf(__expf(a));
    }
    __syncthreads();

#pragma unroll 4
    for (int tt = 0; tt < CL; ++tt) {
        float dtv = s_dt[tt][g];
        float dA  = __expf(dtv * Av);
        h = fmaf(dA, h, dtv * s_uc[tt][g] * s_B[tt][s]);
        float p = h * s_C[tt][s];
        p += __shfl_xor(p, 1);
        p += __shfl_xor(p, 2);
        p += __shfl_xor(p, 4);
        p += __shfl_xor(p, 8);
        if (s == 0) s_y[tt][g] = p;
    }
    __syncthreads();

    for (int e = tid; e < CL * 16; e += 256) {
        int tt = e >> 4, j = e & 15;
        size_t m = (size_t)bc * CL + tt;
        int dg = dch * 16 + j;
        float zv = __bfloat162float(xz[m * 1024 + 512 + dg]);
        float sig = 1.f / (1.f + __expf(-zv));
        float val = (s_y[tt][j] + s_uc[tt][j] * Dp[dg]) * (zv * sig);
        y[m * DIN + dg] = __float2bfloat16(val);
    }
}

// ---------------- launch ----------------------------------------------------
extern "C" void kernel_launch(void* const* d_in, const int* in_sizes, int n_in,
                              void* d_out, int out_size, void* d_ws, size_t ws_size,
                              hipStream_t stream) {
    const float* x         = (const float*)d_in[0];
    const float* proj_w    = (const float*)d_in[1];
    const float* proj_b    = (const float*)d_in[2];
    const float* in_proj_w = (const float*)d_in[3];
    const float* conv_w    = (const float*)d_in[4];
    const float* conv_b    = (const float*)d_in[5];
    const float* x_proj_w  = (const float*)d_in[6];
    const float* dt_proj_w = (const float*)d_in[7];
    const float* dt_proj_b = (const float*)d_in[8];
    const float* A_log     = (const float*)d_in[9];
    const float* Dp        = (const float*)d_in[10];
    const float* out_proj_w= (const float*)d_in[11];
    const float* head_w    = (const float*)d_in[12];
    const float* head_b    = (const float*)d_in[13];
    float* out = (float*)d_out;

    // ---- workspace layout ----
    char* ws = (char*)d_ws;
    __hip_bfloat16* xbf   = (__hip_bfloat16*)ws;  ws += (size_t)MTOT * STIM * 2;   // dead after gemm1
    __hip_bfloat16* hbf   = (__hip_bfloat16*)ws;  ws += (size_t)MTOT * HID * 2;
    __hip_bfloat16* xzbf  = (__hip_bfloat16*)ws;  ws += (size_t)MTOT * 1024 * 2;
    float*          uc    = (float*)ws;           ws += (size_t)MTOT * DIN * 4;
    __hip_bfloat16* ucb   = (__hip_bfloat16*)ws;  ws += (size_t)MTOT * DIN * 2;
    float*          xdb   = (float*)ws;           ws += (size_t)MTOT * 48 * 4;
    __hip_bfloat16* ybf   = (__hip_bfloat16*)ws;  ws += (size_t)MTOT * DIN * 2;
    __hip_bfloat16* obf   = (__hip_bfloat16*)ws;  ws += (size_t)MTOT * HID * 2;
    __hip_bfloat16* wproj = (__hip_bfloat16*)ws;  ws += (size_t)HID * STIM * 2;
    __hip_bfloat16* winp  = (__hip_bfloat16*)ws;  ws += (size_t)(2*DIN) * HID * 2;
    __hip_bfloat16* wout  = (__hip_bfloat16*)ws;  ws += (size_t)HID * DIN * 2;
    __hip_bfloat16* whead = (__hip_bfloat16*)ws;  ws += (size_t)VOX * HID * 2;
    __hip_bfloat16* wxpad = (__hip_bfloat16*)ws;  ws += (size_t)64 * DIN * 2;

    // scan scratch aliases xbf (dead after gemm1): 3 x 8MB <= 32MB
    float* midP   = (float*)xbf;
    float* midS   = midP + (size_t)BB * NCH * DIN * DST;
    float* hstart = midS + (size_t)BB * NCH * DIN * DST;

    dim3 blk(256);

    // ---- conversions ----
    cvt_bf16<<<(MTOT * STIM / 4 + 255) / 256, blk, 0, stream>>>(x, xbf, MTOT * STIM / 4);
    cvt_bf16<<<(HID * STIM / 4 + 255) / 256, blk, 0, stream>>>(proj_w, wproj, HID * STIM / 4);
    cvt_bf16<<<(2 * DIN * HID / 4 + 255) / 256, blk, 0, stream>>>(in_proj_w, winp, 2 * DIN * HID / 4);
    cvt_bf16<<<(HID * DIN / 4 + 255) / 256, blk, 0, stream>>>(out_proj_w, wout, HID * DIN / 4);
    cvt_bf16<<<(VOX * HID / 4 + 255) / 256, blk, 0, stream>>>(head_w, whead, VOX * HID / 4);
    cvt_pad_xproj<<<(64 * DIN) / 256, blk, 0, stream>>>(x_proj_w, wxpad);

    // 1) h = x @ proj_w.T + proj_b          (M=16384, N=256, K=1024) -> bf16
    gemm_bf16<true, true, false><<<dim3(HID / 128, MTOT / 128), blk, 0, stream>>>(
        xbf, STIM, wproj, STIM, proj_b, hbf, HID, STIM);

    // 2) xz = h @ in_proj_w.T               (M=16384, N=1024, K=256) -> bf16
    gemm_bf16<false, true, false><<<dim3(1024 / 128, MTOT / 128), blk, 0, stream>>>(
        hbf, HID, winp, HID, nullptr, xzbf, 1024, HID);

    // 3) uc = silu(conv(u))  -> fp32 + bf16
    conv_silu<<<(MTOT * DIN / 8) / 256, blk, 0, stream>>>(xzbf, conv_w, conv_b, uc, ucb);

    // 4) xdb = ucb @ wxpad^T  (MFMA, masked n<48)
    gemm_xdb<<<MTOT / 64, blk, 0, stream>>>(ucb, wxpad, xdb);

    // 5/6) chunked selective scan with fused dt-projection + epilogue
    scan_pass1<<<BB * NCH * 32, blk, 0, stream>>>(xdb, uc, dt_proj_w, dt_proj_b, A_log, midP, midS);
    scan_pass2<<<BB * DIN * DST / 256, blk, 0, stream>>>(midP, midS, hstart);
    scan_pass3<<<BB * NCH * 32, blk, 0, stream>>>(xdb, uc, dt_proj_w, dt_proj_b, xzbf, A_log, Dp, hstart, ybf);

    // 7) o = y @ out_proj_w.T               (M=16384, N=256, K=512) -> bf16
    gemm_bf16<false, true, false><<<dim3(HID / 128, MTOT / 128), blk, 0, stream>>>(
        ybf, DIN, wout, DIN, nullptr, obf, HID, DIN);

    // 8) out = o @ head_w.T + head_b        (M=16384, N=8192, K=256) fp32 out, XCD-swizzled
    gemm_bf16<true, false, true><<<dim3(VOX / 128, MTOT / 128), blk, 0, stream>>>(
        obf, HID, whead, HID, head_b, out, VOX, HID);
}

// Round 6
// 509.873 us; speedup vs baseline: 3.9145x; 1.0830x over previous
//
#include <hip/hip_runtime.h>
#include <hip/hip_bf16.h>

// ---------------- Problem constants ----------------
#define BB     8
#define LSEQ   2048
#define MTOT   (BB*LSEQ)     // 16384
#define STIM   1024
#define HID    256
#define VOX    8192
#define DIN    512           // D_INNER
#define DST    16            // D_STATE
#define DCONV  4
#define DTR    16            // DT_RANK
#define NCH    32            // scan chunks
#define CL     64            // chunk length (NCH*CL == LSEQ)

typedef __attribute__((ext_vector_type(8))) short bf16x8;
typedef __attribute__((ext_vector_type(4))) float f32x4;

// ---------------- async global->LDS 16B helper -----------------------------
__device__ __forceinline__ void load_lds16(const void* g, void* l) {
    __builtin_amdgcn_global_load_lds(
        (const __attribute__((address_space(1))) unsigned int*)g,
        (__attribute__((address_space(3))) unsigned int*)l, 16, 0, 0);
}

__device__ __forceinline__ float bf2f(short s) {
    union { short x; __hip_bfloat16 h; } cv; cv.x = s;
    return __bfloat162float(cv.h);
}

// ---------------- fp32 -> bf16 conversion (x input) ------------------------
__global__ __launch_bounds__(256) void cvt_bf16(
    const float* __restrict__ in, __hip_bfloat16* __restrict__ out, int n4)
{
    int i = blockIdx.x * 256 + threadIdx.x;
    if (i < n4) {
        float4 a = ((const float4*)in)[i];
        union { __hip_bfloat16 h[4]; ushort4 u; } cv;
        cv.h[0] = __float2bfloat16(a.x);
        cv.h[1] = __float2bfloat16(a.y);
        cv.h[2] = __float2bfloat16(a.z);
        cv.h[3] = __float2bfloat16(a.w);
        ((ushort4*)out)[i] = cv.u;
    }
}

// ---------------- all weight conversions fused (incl. zero-padded x_proj) --
__global__ __launch_bounds__(256) void cvt_weights(
    const float* __restrict__ proj_w, const float* __restrict__ in_proj_w,
    const float* __restrict__ out_proj_w, const float* __restrict__ head_w,
    const float* __restrict__ x_proj_w,
    __hip_bfloat16* __restrict__ wproj, __hip_bfloat16* __restrict__ winp,
    __hip_bfloat16* __restrict__ wout, __hip_bfloat16* __restrict__ whead,
    __hip_bfloat16* __restrict__ wxpad)
{
    const int N0 = 65536, N1 = N0 + 65536, N2 = N1 + 32768, N3 = N2 + 524288, N4 = N3 + 8192;
    for (int i = blockIdx.x * 256 + threadIdx.x; i < N4; i += gridDim.x * 256) {
        float4 a;
        __hip_bfloat16* dst; int off;
        if (i < N0)      { a = ((const float4*)proj_w)[i];          dst = wproj; off = i; }
        else if (i < N1) { a = ((const float4*)in_proj_w)[i - N0];  dst = winp;  off = i - N0; }
        else if (i < N2) { a = ((const float4*)out_proj_w)[i - N1]; dst = wout;  off = i - N1; }
        else if (i < N3) { a = ((const float4*)head_w)[i - N2];     dst = whead; off = i - N2; }
        else {
            off = i - N3;
            int el = off * 4, row = el >> 9;
            a = (row < 48) ? ((const float4*)x_proj_w)[(row * 512 + (el & 511)) >> 2]
                           : make_float4(0.f, 0.f, 0.f, 0.f);
            dst = wxpad;
        }
        union { __hip_bfloat16 h[4]; ushort4 u; } cv;
        cv.h[0] = __float2bfloat16(a.x);
        cv.h[1] = __float2bfloat16(a.y);
        cv.h[2] = __float2bfloat16(a.z);
        cv.h[3] = __float2bfloat16(a.w);
        ((ushort4*)dst)[off] = cv.u;
    }
}

// ---------------- bf16 MFMA TN GEMM, 128x128 tile (for wide N) -------------
template<bool BIAS, bool OUT_BF16, bool SWZ>
__global__ __launch_bounds__(256) void gemm_bf16(
    const __hip_bfloat16* __restrict__ A, int lda,
    const __hip_bfloat16* __restrict__ W, int ldw,
    const float* __restrict__ bias,
    void* __restrict__ C, int ldc, int K)
{
    __shared__ __hip_bfloat16 As[128 * 32];
    __shared__ __hip_bfloat16 Bs[128 * 32];

    const int tid  = threadIdx.x;
    const int lane = tid & 63;
    const int wave = tid >> 6;
    const int wr = wave >> 1, wc = wave & 1;

    int bx = blockIdx.x, by = blockIdx.y;
    if (SWZ) {
        int nwg = gridDim.x * gridDim.y;
        int wg  = by * gridDim.x + bx;
        wg = (wg & 7) * (nwg >> 3) + (wg >> 3);   // bijective: nwg % 8 == 0
        bx = wg % gridDim.x;
        by = wg / gridDim.x;
    }
    const int bm = by * 128, bn = bx * 128;

    f32x4 acc[4][4];
#pragma unroll
    for (int i = 0; i < 4; ++i)
#pragma unroll
        for (int j = 0; j < 4; ++j) acc[i][j] = f32x4{0.f, 0.f, 0.f, 0.f};

    const int srow = tid >> 2;
    const int col8 = (tid & 3) * 8;

    for (int k0 = 0; k0 < K; k0 += 32) {
        load_lds16(A + (size_t)(bm + srow)      * lda + k0 + col8, &As[(size_t)tid * 8]);
        load_lds16(A + (size_t)(bm + 64 + srow) * lda + k0 + col8, &As[(size_t)(256 + tid) * 8]);
        load_lds16(W + (size_t)(bn + srow)      * ldw + k0 + col8, &Bs[(size_t)tid * 8]);
        load_lds16(W + (size_t)(bn + 64 + srow) * ldw + k0 + col8, &Bs[(size_t)(256 + tid) * 8]);
        __syncthreads();

        const int kk = (lane >> 4) * 8;
        bf16x8 af[4], bfr[4];
#pragma unroll
        for (int i = 0; i < 4; ++i) {
            af[i]  = *(const bf16x8*)&As[(wr * 64 + i * 16 + (lane & 15)) * 32 + kk];
            bfr[i] = *(const bf16x8*)&Bs[(wc * 64 + i * 16 + (lane & 15)) * 32 + kk];
        }
#pragma unroll
        for (int i = 0; i < 4; ++i)
#pragma unroll
            for (int j = 0; j < 4; ++j)
                acc[i][j] = __builtin_amdgcn_mfma_f32_16x16x32_bf16(af[i], bfr[j], acc[i][j], 0, 0, 0);
        __syncthreads();
    }

#pragma unroll
    for (int i = 0; i < 4; ++i) {
        int m = bm + wr * 64 + i * 16 + (lane >> 4) * 4;
#pragma unroll
        for (int j = 0; j < 4; ++j) {
            int n = bn + wc * 64 + j * 16 + (lane & 15);
            float bv = BIAS ? bias[n] : 0.f;
#pragma unroll
            for (int r = 0; r < 4; ++r) {
                float v = acc[i][j][r] + bv;
                if (OUT_BF16)
                    ((__hip_bfloat16*)C)[(size_t)(m + r) * ldc + n] = __float2bfloat16(v);
                else
                    ((float*)C)[(size_t)(m + r) * ldc + n] = v;
            }
        }
    }
}

// ---------------- bf16 MFMA TN GEMM, 64x64 tile (for skinny N: occupancy) --
template<bool BIAS, bool OUT_BF16, bool SWZ>
__global__ __launch_bounds__(256) void gemm64(
    const __hip_bfloat16* __restrict__ A, int lda,
    const __hip_bfloat16* __restrict__ W, int ldw,
    const float* __restrict__ bias,
    void* __restrict__ C, int ldc, int K)
{
    __shared__ __hip_bfloat16 As[64 * 32];
    __shared__ __hip_bfloat16 Bs[64 * 32];

    const int tid  = threadIdx.x;
    const int lane = tid & 63;
    const int wave = tid >> 6;
    const int wr = wave >> 1, wc = wave & 1;

    int bx = blockIdx.x, by = blockIdx.y;
    if (SWZ) {
        int nwg = gridDim.x * gridDim.y;
        int wg  = by * gridDim.x + bx;
        wg = (wg & 7) * (nwg >> 3) + (wg >> 3);
        bx = wg % gridDim.x;
        by = wg / gridDim.x;
    }
    const int bm = by * 64, bn = bx * 64;

    f32x4 acc[2][2];
#pragma unroll
    for (int i = 0; i < 2; ++i)
#pragma unroll
        for (int j = 0; j < 2; ++j) acc[i][j] = f32x4{0.f, 0.f, 0.f, 0.f};

    const int srow = tid >> 2;
    const int col8 = (tid & 3) * 8;

    for (int k0 = 0; k0 < K; k0 += 32) {
        load_lds16(A + (size_t)(bm + srow) * lda + k0 + col8, &As[(size_t)tid * 8]);
        load_lds16(W + (size_t)(bn + srow) * ldw + k0 + col8, &Bs[(size_t)tid * 8]);
        __syncthreads();

        const int kk = (lane >> 4) * 8;
        bf16x8 af[2], bfr[2];
#pragma unroll
        for (int i = 0; i < 2; ++i) {
            af[i]  = *(const bf16x8*)&As[(wr * 32 + i * 16 + (lane & 15)) * 32 + kk];
            bfr[i] = *(const bf16x8*)&Bs[(wc * 32 + i * 16 + (lane & 15)) * 32 + kk];
        }
#pragma unroll
        for (int i = 0; i < 2; ++i)
#pragma unroll
            for (int j = 0; j < 2; ++j)
                acc[i][j] = __builtin_amdgcn_mfma_f32_16x16x32_bf16(af[i], bfr[j], acc[i][j], 0, 0, 0);
        __syncthreads();
    }

#pragma unroll
    for (int i = 0; i < 2; ++i) {
        int m = bm + wr * 32 + i * 16 + (lane >> 4) * 4;
#pragma unroll
        for (int j = 0; j < 2; ++j) {
            int n = bn + wc * 32 + j * 16 + (lane & 15);
            float bv = BIAS ? bias[n] : 0.f;
#pragma unroll
            for (int r = 0; r < 4; ++r) {
                float v = acc[i][j][r] + bv;
                if (OUT_BF16)
                    ((__hip_bfloat16*)C)[(size_t)(m + r) * ldc + n] = __float2bfloat16(v);
                else
                    ((float*)C)[(size_t)(m + r) * ldc + n] = v;
            }
        }
    }
}

// ---------------- xdb = ucb @ wxpad^T  (M=16384, N=48 of 64, K=512) --------
__global__ __launch_bounds__(256) void gemm_xdb(
    const __hip_bfloat16* __restrict__ A,    // ucb (MTOT,512)
    const __hip_bfloat16* __restrict__ W,    // wxpad (64,512)
    float* __restrict__ C)                   // xdb (MTOT,48)
{
    __shared__ __hip_bfloat16 As[64 * 32];
    __shared__ __hip_bfloat16 Bs[64 * 32];

    const int tid  = threadIdx.x;
    const int lane = tid & 63;
    const int wave = tid >> 6;
    const int wr = wave >> 1, wc = wave & 1;
    const int bm = blockIdx.x * 64;

    f32x4 acc[2][2];
#pragma unroll
    for (int i = 0; i < 2; ++i)
#pragma unroll
        for (int j = 0; j < 2; ++j) acc[i][j] = f32x4{0.f, 0.f, 0.f, 0.f};

    const int srow = tid >> 2;
    const int col8 = (tid & 3) * 8;

    for (int k0 = 0; k0 < DIN; k0 += 32) {
        load_lds16(A + (size_t)(bm + srow) * DIN + k0 + col8, &As[(size_t)tid * 8]);
        load_lds16(W + (size_t)srow * DIN + k0 + col8, &Bs[(size_t)tid * 8]);
        __syncthreads();

        const int kk = (lane >> 4) * 8;
        bf16x8 af[2], bfr[2];
#pragma unroll
        for (int i = 0; i < 2; ++i) {
            af[i]  = *(const bf16x8*)&As[(wr * 32 + i * 16 + (lane & 15)) * 32 + kk];
            bfr[i] = *(const bf16x8*)&Bs[(wc * 32 + i * 16 + (lane & 15)) * 32 + kk];
        }
#pragma unroll
        for (int i = 0; i < 2; ++i)
#pragma unroll
            for (int j = 0; j < 2; ++j)
                acc[i][j] = __builtin_amdgcn_mfma_f32_16x16x32_bf16(af[i], bfr[j], acc[i][j], 0, 0, 0);
        __syncthreads();
    }

#pragma unroll
    for (int i = 0; i < 2; ++i) {
        int m = bm + wr * 32 + i * 16 + (lane >> 4) * 4;
#pragma unroll
        for (int j = 0; j < 2; ++j) {
            int n = wc * 32 + j * 16 + (lane & 15);
            if (n < 48) {
#pragma unroll
                for (int r = 0; r < 4; ++r)
                    C[(size_t)(m + r) * 48 + n] = acc[i][j][r];
            }
        }
    }
}

// ---------------- conv1d + SiLU -> ucb (bf16 only) -------------------------
__global__ __launch_bounds__(256) void conv_silu(
    const __hip_bfloat16* __restrict__ xz, const float* __restrict__ conv_w,
    const float* __restrict__ conv_b, __hip_bfloat16* __restrict__ ucb)
{
    int idx = blockIdx.x * 256 + threadIdx.x;   // over MTOT*DIN/8
    int d8  = (idx & 63) * 8;
    int m   = idx >> 6;
    int l   = m & (LSEQ - 1);

    float4 w4[8];
#pragma unroll
    for (int j = 0; j < 8; ++j) w4[j] = *(const float4*)(conv_w + (d8 + j) * 4);

    float acc[8];
    {
        float4 b0 = *(const float4*)(conv_b + d8);
        float4 b1 = *(const float4*)(conv_b + d8 + 4);
        acc[0]=b0.x; acc[1]=b0.y; acc[2]=b0.z; acc[3]=b0.w;
        acc[4]=b1.x; acc[5]=b1.y; acc[6]=b1.z; acc[7]=b1.w;
    }
#pragma unroll
    for (int k = 0; k < DCONV; ++k) {
        int lk = l + k - (DCONV - 1);
        if (lk >= 0) {
            bf16x8 v = *(const bf16x8*)(xz + (size_t)(m + k - (DCONV - 1)) * 1024 + d8);
#pragma unroll
            for (int j = 0; j < 8; ++j) {
                float w = (k == 0) ? w4[j].x : (k == 1) ? w4[j].y : (k == 2) ? w4[j].z : w4[j].w;
                acc[j] = fmaf(w, bf2f(v[j]), acc[j]);
            }
        }
    }

    bf16x8 ob;
#pragma unroll
    for (int j = 0; j < 8; ++j) {
        float sig = 1.f / (1.f + __expf(-acc[j]));
        float v = acc[j] * sig;
        union { __hip_bfloat16 h; short s; } cv; cv.h = __float2bfloat16(v);
        ob[j] = cv.s;
    }
    *(bf16x8*)(ucb + (size_t)m * DIN + d8) = ob;
}

// ---------------- chunked selective scan (dt fused; ucb bf16 input) ---------
__global__ __launch_bounds__(256) void scan_pass1(
    const float* __restrict__ xdb, const __hip_bfloat16* __restrict__ ucb,
    const float* __restrict__ dtw, const float* __restrict__ dtbias,
    const float* __restrict__ A_log,
    float* __restrict__ midP, float* __restrict__ midS)
{
    __shared__ float s_dt[CL][16], s_uc[CL][16], s_B[CL][16], s_xt[CL][16];
    __shared__ float s_w[16][17];
    __shared__ float s_bias[16];
    const int tid = threadIdx.x;
    const int blk = blockIdx.x;        // (b*NCH + c)*32 + dch
    const int dch = blk & 31;
    const int bc  = blk >> 5;
    const int g = tid >> 4, s = tid & 15;
    const int d = dch * 16 + g;
    const float Av = -__expf(A_log[d * DST + s]);

    {
        int row = tid >> 2, q = tid & 3;
        size_t m = (size_t)bc * CL + row;
        *(float4*)&s_B[row][q*4]  = *(const float4*)(xdb + m * 48 + 16 + q * 4);
        *(float4*)&s_xt[row][q*4] = *(const float4*)(xdb + m * 48 + q * 4);
        s_w[tid >> 4][tid & 15] = dtw[(dch * 16 + (tid >> 4)) * DTR + (tid & 15)];
        if (tid < 16) s_bias[tid] = dtbias[dch * 16 + tid];
    }
    if (tid < 128) {
        int row = tid >> 1, q = tid & 1;
        size_t m = (size_t)bc * CL + row;
        bf16x8 v = *(const bf16x8*)(ucb + m * DIN + dch * 16 + q * 8);
#pragma unroll
        for (int j = 0; j < 8; ++j) s_uc[row][q * 8 + j] = bf2f(v[j]);
    }
    __syncthreads();

    // dt for 64 rows x 16 channels
#pragma unroll
    for (int p = 0; p < 4; ++p) {
        int e = p * 256 + tid;
        int tt = e >> 4, gg = e & 15;
        float a = s_bias[gg];
#pragma unroll
        for (int r = 0; r < DTR; ++r)
            a = fmaf(s_xt[tt][r], s_w[gg][r], a);
        s_dt[tt][gg] = (a > 20.f) ? a : log1pf(__expf(a));
    }
    __syncthreads();

    float h = 0.f, sdt = 0.f;
#pragma unroll 8
    for (int tt = 0; tt < CL; ++tt) {
        float dtv = s_dt[tt][g];
        float dA  = __expf(dtv * Av);
        h = fmaf(dA, h, dtv * s_uc[tt][g] * s_B[tt][s]);
        sdt += dtv;
    }
    size_t o = (size_t)blk * 256 + tid;
    midP[o] = __expf(sdt * Av);
    midS[o] = h;
}

__global__ __launch_bounds__(256) void scan_pass2(
    const float* __restrict__ midP, const float* __restrict__ midS,
    float* __restrict__ hstart)
{
    int t = blockIdx.x * 256 + threadIdx.x;
    int b  = t >> 13;
    int ds = t & 8191;
    float h = 0.f;
#pragma unroll
    for (int c = 0; c < NCH; ++c) {
        size_t o = ((size_t)(b * NCH + c) << 13) + ds;
        hstart[o] = h;
        h = fmaf(midP[o], h, midS[o]);
    }
}

__global__ __launch_bounds__(256) void scan_pass3(
    const float* __restrict__ xdb, const __hip_bfloat16* __restrict__ ucb,
    const float* __restrict__ dtw, const float* __restrict__ dtbias,
    const __hip_bfloat16* __restrict__ xz,
    const float* __restrict__ A_log, const float* __restrict__ Dp,
    const float* __restrict__ hstart, __hip_bfloat16* __restrict__ y)
{
    __shared__ float s_dt[CL][16], s_uc[CL][16], s_B[CL][16], s_C[CL][16], s_xt[CL][16], s_y[CL][16];
    __shared__ float s_w[16][17];
    __shared__ float s_bias[16];
    const int tid = threadIdx.x;
    const int blk = blockIdx.x;
    const int dch = blk & 31;
    const int bc  = blk >> 5;
    const int g = tid >> 4, s = tid & 15;
    const int d = dch * 16 + g;
    const float Av = -__expf(A_log[d * DST + s]);

    {
        int row = tid >> 2, q = tid & 3;
        size_t m = (size_t)bc * CL + row;
        *(float4*)&s_B[row][q*4]  = *(const float4*)(xdb + m * 48 + 16 + q * 4);
        *(float4*)&s_C[row][q*4]  = *(const float4*)(xdb + m * 48 + 32 + q * 4);
        *(float4*)&s_xt[row][q*4] = *(const float4*)(xdb + m * 48 + q * 4);
        s_w[tid >> 4][tid & 15] = dtw[(dch * 16 + (tid >> 4)) * DTR + (tid & 15)];
        if (tid < 16) s_bias[tid] = dtbias[dch * 16 + tid];
    }
    if (tid < 128) {
        int row = tid >> 1, q = tid & 1;
        size_t m = (size_t)bc * CL + row;
        bf16x8 v = *(const bf16x8*)(ucb + m * DIN + dch * 16 + q * 8);
#pragma unroll
        for (int j = 0; j < 8; ++j) s_uc[row][q * 8 + j] = bf2f(v[j]);
    }
    float h = hstart[(size_t)blk * 256 + tid];
    __syncthreads();

#pragma unroll
    for (int p = 0; p < 4; ++p) {
        int e = p * 256 + tid;
        int tt = e >> 4, gg = e & 15;
        float a = s_bias[gg];
#pragma unroll
        for (int r = 0; r < DTR; ++r)
            a = fmaf(s_xt[tt][r], s_w[gg][r], a);
        s_dt[tt][gg] = (a > 20.f) ? a : log1pf(__expf(a));
    }
    __syncthreads();

#pragma unroll 4
    for (int tt = 0; tt < CL; ++tt) {
        float dtv = s_dt[tt][g];
        float dA  = __expf(dtv * Av);
        h = fmaf(dA, h, dtv * s_uc[tt][g] * s_B[tt][s]);
        float p = h * s_C[tt][s];
        p += __shfl_xor(p, 1);
        p += __shfl_xor(p, 2);
        p += __shfl_xor(p, 4);
        p += __shfl_xor(p, 8);
        if (s == 0) s_y[tt][g] = p;
    }
    __syncthreads();

    for (int e = tid; e < CL * 16; e += 256) {
        int tt = e >> 4, j = e & 15;
        size_t m = (size_t)bc * CL + tt;
        int dg = dch * 16 + j;
        float zv = __bfloat162float(xz[m * 1024 + 512 + dg]);
        float sig = 1.f / (1.f + __expf(-zv));
        float val = (s_y[tt][j] + s_uc[tt][j] * Dp[dg]) * (zv * sig);
        y[m * DIN + dg] = __float2bfloat16(val);
    }
}

// ---------------- launch ----------------------------------------------------
extern "C" void kernel_launch(void* const* d_in, const int* in_sizes, int n_in,
                              void* d_out, int out_size, void* d_ws, size_t ws_size,
                              hipStream_t stream) {
    const float* x         = (const float*)d_in[0];
    const float* proj_w    = (const float*)d_in[1];
    const float* proj_b    = (const float*)d_in[2];
    const float* in_proj_w = (const float*)d_in[3];
    const float* conv_w    = (const float*)d_in[4];
    const float* conv_b    = (const float*)d_in[5];
    const float* x_proj_w  = (const float*)d_in[6];
    const float* dt_proj_w = (const float*)d_in[7];
    const float* dt_proj_b = (const float*)d_in[8];
    const float* A_log     = (const float*)d_in[9];
    const float* Dp        = (const float*)d_in[10];
    const float* out_proj_w= (const float*)d_in[11];
    const float* head_w    = (const float*)d_in[12];
    const float* head_b    = (const float*)d_in[13];
    float* out = (float*)d_out;

    // ---- workspace layout ----
    char* ws = (char*)d_ws;
    __hip_bfloat16* xbf   = (__hip_bfloat16*)ws;  ws += (size_t)MTOT * STIM * 2;   // dead after gemm1
    __hip_bfloat16* hbf   = (__hip_bfloat16*)ws;  ws += (size_t)MTOT * HID * 2;
    __hip_bfloat16* xzbf  = (__hip_bfloat16*)ws;  ws += (size_t)MTOT * 1024 * 2;
    __hip_bfloat16* ucb   = (__hip_bfloat16*)ws;  ws += (size_t)MTOT * DIN * 2;
    float*          xdb   = (float*)ws;           ws += (size_t)MTOT * 48 * 4;
    __hip_bfloat16* ybf   = (__hip_bfloat16*)ws;  ws += (size_t)MTOT * DIN * 2;
    __hip_bfloat16* obf   = (__hip_bfloat16*)ws;  ws += (size_t)MTOT * HID * 2;
    __hip_bfloat16* wproj = (__hip_bfloat16*)ws;  ws += (size_t)HID * STIM * 2;
    __hip_bfloat16* winp  = (__hip_bfloat16*)ws;  ws += (size_t)(2*DIN) * HID * 2;
    __hip_bfloat16* wout  = (__hip_bfloat16*)ws;  ws += (size_t)HID * DIN * 2;
    __hip_bfloat16* whead = (__hip_bfloat16*)ws;  ws += (size_t)VOX * HID * 2;
    __hip_bfloat16* wxpad = (__hip_bfloat16*)ws;  ws += (size_t)64 * DIN * 2;

    // scan scratch aliases xbf (dead after gemm1): 3 x 8MB <= 32MB
    float* midP   = (float*)xbf;
    float* midS   = midP + (size_t)BB * NCH * DIN * DST;
    float* hstart = midS + (size_t)BB * NCH * DIN * DST;

    dim3 blk(256);

    // ---- conversions ----
    cvt_bf16<<<(MTOT * STIM / 4 + 255) / 256, blk, 0, stream>>>(x, xbf, MTOT * STIM / 4);
    cvt_weights<<<2048, blk, 0, stream>>>(proj_w, in_proj_w, out_proj_w, head_w, x_proj_w,
                                          wproj, winp, wout, whead, wxpad);

    // 1) h = x @ proj_w.T + proj_b          (M=16384, N=256, K=1024) -> bf16 (64-tile, 1024 blocks)
    gemm64<true, true, true><<<dim3(HID / 64, MTOT / 64), blk, 0, stream>>>(
        xbf, STIM, wproj, STIM, proj_b, hbf, HID, STIM);

    // 2) xz = h @ in_proj_w.T               (M=16384, N=1024, K=256) -> bf16
    gemm_bf16<false, true, true><<<dim3(1024 / 128, MTOT / 128), blk, 0, stream>>>(
        hbf, HID, winp, HID, nullptr, xzbf, 1024, HID);

    // 3) ucb = silu(conv(u))  -> bf16 only
    conv_silu<<<(MTOT * DIN / 8) / 256, blk, 0, stream>>>(xzbf, conv_w, conv_b, ucb);

    // 4) xdb = ucb @ wxpad^T  (MFMA, masked n<48)
    gemm_xdb<<<MTOT / 64, blk, 0, stream>>>(ucb, wxpad, xdb);

    // 5/6) chunked selective scan with fused dt-projection + epilogue
    scan_pass1<<<BB * NCH * 32, blk, 0, stream>>>(xdb, ucb, dt_proj_w, dt_proj_b, A_log, midP, midS);
    scan_pass2<<<BB * DIN * DST / 256, blk, 0, stream>>>(midP, midS, hstart);
    scan_pass3<<<BB * NCH * 32, blk, 0, stream>>>(xdb, ucb, dt_proj_w, dt_proj_b, xzbf, A_log, Dp, hstart, ybf);

    // 7) o = y @ out_proj_w.T               (M=16384, N=256, K=512) -> bf16 (64-tile)
    gemm64<false, true, true><<<dim3(HID / 64, MTOT / 64), blk, 0, stream>>>(
        ybf, DIN, wout, DIN, nullptr, obf, HID, DIN);

    // 8) out = o @ head_w.T + head_b        (M=16384, N=8192, K=256) fp32 out, XCD-swizzled
    gemm_bf16<true, false, true><<<dim3(VOX / 128, MTOT / 128), blk, 0, stream>>>(
        obf, HID, whead, HID, head_b, out, VOX, HID);
}

// Round 7
// 487.028 us; speedup vs baseline: 4.0981x; 1.0469x over previous
//
#include <hip/hip_runtime.h>
#include <hip/hip_bf16.h>

// ---------------- Problem constants ----------------
#define BB     8
#define LSEQ   2048
#define MTOT   (BB*LSEQ)     // 16384
#define STIM   1024
#define HID    256
#define VOX    8192
#define DIN    512           // D_INNER
#define DST    16            // D_STATE
#define DCONV  4
#define DTR    16            // DT_RANK
#define NCH    32            // scan chunks
#define CL     64            // chunk length (NCH*CL == LSEQ)

typedef __attribute__((ext_vector_type(8))) short bf16x8;
typedef __attribute__((ext_vector_type(4))) float f32x4;

// ---------------- async global->LDS 16B helper -----------------------------
__device__ __forceinline__ void load_lds16(const void* g, void* l) {
    __builtin_amdgcn_global_load_lds(
        (const __attribute__((address_space(1))) unsigned int*)g,
        (__attribute__((address_space(3))) unsigned int*)l, 16, 0, 0);
}

__device__ __forceinline__ float bf2f(short s) {
    union { short x; __hip_bfloat16 h; } cv; cv.x = s;
    return __bfloat162float(cv.h);
}

// row-grouped XCD swizzle: keep all N-blocks of a row-group on one XCD.
// Requires gridDim.y % 8 == 0.
__device__ __forceinline__ void swz_rowgrp(int& bx, int& by) {
    int gx = gridDim.x;
    int h   = by * gx + bx;
    int xcd = h & 7;
    int idx = h >> 3;
    int gpx = gridDim.y >> 3;          // row-groups per XCD
    by = xcd * gpx + idx / gx;
    bx = idx % gx;
}

// ---------------- all weight conversions fused (incl. zero-padded x_proj) --
__global__ __launch_bounds__(256) void cvt_weights(
    const float* __restrict__ proj_w, const float* __restrict__ in_proj_w,
    const float* __restrict__ out_proj_w, const float* __restrict__ head_w,
    const float* __restrict__ x_proj_w,
    __hip_bfloat16* __restrict__ wproj, __hip_bfloat16* __restrict__ winp,
    __hip_bfloat16* __restrict__ wout, __hip_bfloat16* __restrict__ whead,
    __hip_bfloat16* __restrict__ wxpad)
{
    const int N0 = 65536, N1 = N0 + 65536, N2 = N1 + 32768, N3 = N2 + 524288, N4 = N3 + 8192;
    for (int i = blockIdx.x * 256 + threadIdx.x; i < N4; i += gridDim.x * 256) {
        float4 a;
        __hip_bfloat16* dst; int off;
        if (i < N0)      { a = ((const float4*)proj_w)[i];          dst = wproj; off = i; }
        else if (i < N1) { a = ((const float4*)in_proj_w)[i - N0];  dst = winp;  off = i - N0; }
        else if (i < N2) { a = ((const float4*)out_proj_w)[i - N1]; dst = wout;  off = i - N1; }
        else if (i < N3) { a = ((const float4*)head_w)[i - N2];     dst = whead; off = i - N2; }
        else {
            off = i - N3;
            int el = off * 4, row = el >> 9;
            a = (row < 48) ? ((const float4*)x_proj_w)[(row * 512 + (el & 511)) >> 2]
                           : make_float4(0.f, 0.f, 0.f, 0.f);
            dst = wxpad;
        }
        union { __hip_bfloat16 h[4]; ushort4 u; } cv;
        cv.h[0] = __float2bfloat16(a.x);
        cv.h[1] = __float2bfloat16(a.y);
        cv.h[2] = __float2bfloat16(a.z);
        cv.h[3] = __float2bfloat16(a.w);
        ((ushort4*)dst)[off] = cv.u;
    }
}

// ---------------- GEMM-1: A fp32 (cvt in staging), 64x128 tile -------------
// C[M,N] = A[M,K](fp32) @ W[N,K]^T(bf16) + bias -> bf16.  4 waves = 2(m)x2(n),
// wave-tile 32x64.
__global__ __launch_bounds__(256) void gemm_a32(
    const float* __restrict__ A, int lda,
    const __hip_bfloat16* __restrict__ W, int ldw,
    const float* __restrict__ bias,
    __hip_bfloat16* __restrict__ C, int ldc, int K)
{
    __shared__ __hip_bfloat16 As[64 * 32];
    __shared__ __hip_bfloat16 Bs[128 * 32];

    const int tid  = threadIdx.x;
    const int lane = tid & 63;
    const int wave = tid >> 6;
    const int wr = wave >> 1, wc = wave & 1;

    int bx = blockIdx.x, by = blockIdx.y;
    swz_rowgrp(bx, by);
    const int bm = by * 64, bn = bx * 128;

    f32x4 acc[2][4];
#pragma unroll
    for (int i = 0; i < 2; ++i)
#pragma unroll
        for (int j = 0; j < 4; ++j) acc[i][j] = f32x4{0.f, 0.f, 0.f, 0.f};

    const int arow = tid >> 2;           // 0..63
    const int ac8  = (tid & 3) * 8;

    for (int k0 = 0; k0 < K; k0 += 32) {
        // W tile: 128x32 bf16 via global_load_lds (2 x 16B per thread)
#pragma unroll
        for (int p = 0; p < 2; ++p) {
            int idx = tid + p * 256;
            int row = idx >> 2, c8 = (idx & 3) * 8;
            load_lds16(W + (size_t)(bn + row) * ldw + k0 + c8, &Bs[(size_t)idx * 8]);
        }
        // A tile: 64x32 fp32 -> cvt -> LDS bf16
        {
            const float* ap = A + (size_t)(bm + arow) * lda + k0 + ac8;
            float4 f0 = *(const float4*)ap;
            float4 f1 = *(const float4*)(ap + 4);
            union { __hip_bfloat16 h[8]; bf16x8 v; } cv;
            cv.h[0] = __float2bfloat16(f0.x); cv.h[1] = __float2bfloat16(f0.y);
            cv.h[2] = __float2bfloat16(f0.z); cv.h[3] = __float2bfloat16(f0.w);
            cv.h[4] = __float2bfloat16(f1.x); cv.h[5] = __float2bfloat16(f1.y);
            cv.h[6] = __float2bfloat16(f1.z); cv.h[7] = __float2bfloat16(f1.w);
            *(bf16x8*)&As[arow * 32 + ac8] = cv.v;
        }
        __syncthreads();

        const int kk = (lane >> 4) * 8;
        bf16x8 af[2], bfr[4];
#pragma unroll
        for (int i = 0; i < 2; ++i)
            af[i] = *(const bf16x8*)&As[(wr * 32 + i * 16 + (lane & 15)) * 32 + kk];
#pragma unroll
        for (int j = 0; j < 4; ++j)
            bfr[j] = *(const bf16x8*)&Bs[(wc * 64 + j * 16 + (lane & 15)) * 32 + kk];
#pragma unroll
        for (int i = 0; i < 2; ++i)
#pragma unroll
            for (int j = 0; j < 4; ++j)
                acc[i][j] = __builtin_amdgcn_mfma_f32_16x16x32_bf16(af[i], bfr[j], acc[i][j], 0, 0, 0);
        __syncthreads();
    }

#pragma unroll
    for (int i = 0; i < 2; ++i) {
        int m = bm + wr * 32 + i * 16 + (lane >> 4) * 4;
#pragma unroll
        for (int j = 0; j < 4; ++j) {
            int n = bn + wc * 64 + j * 16 + (lane & 15);
            float bv = bias ? bias[n] : 0.f;
#pragma unroll
            for (int r = 0; r < 4; ++r)
                C[(size_t)(m + r) * ldc + n] = __float2bfloat16(acc[i][j][r] + bv);
        }
    }
}

// ---------------- bf16 MFMA TN GEMM, 128x128 tile --------------------------
template<bool BIAS, bool OUT_BF16, bool NT>
__global__ __launch_bounds__(256) void gemm_bf16(
    const __hip_bfloat16* __restrict__ A, int lda,
    const __hip_bfloat16* __restrict__ W, int ldw,
    const float* __restrict__ bias,
    void* __restrict__ C, int ldc, int K)
{
    __shared__ __hip_bfloat16 As[128 * 32];
    __shared__ __hip_bfloat16 Bs[128 * 32];

    const int tid  = threadIdx.x;
    const int lane = tid & 63;
    const int wave = tid >> 6;
    const int wr = wave >> 1, wc = wave & 1;

    int bx = blockIdx.x, by = blockIdx.y;
    swz_rowgrp(bx, by);
    const int bm = by * 128, bn = bx * 128;

    f32x4 acc[4][4];
#pragma unroll
    for (int i = 0; i < 4; ++i)
#pragma unroll
        for (int j = 0; j < 4; ++j) acc[i][j] = f32x4{0.f, 0.f, 0.f, 0.f};

    const int srow = tid >> 2;
    const int col8 = (tid & 3) * 8;

    for (int k0 = 0; k0 < K; k0 += 32) {
        load_lds16(A + (size_t)(bm + srow)      * lda + k0 + col8, &As[(size_t)tid * 8]);
        load_lds16(A + (size_t)(bm + 64 + srow) * lda + k0 + col8, &As[(size_t)(256 + tid) * 8]);
        load_lds16(W + (size_t)(bn + srow)      * ldw + k0 + col8, &Bs[(size_t)tid * 8]);
        load_lds16(W + (size_t)(bn + 64 + srow) * ldw + k0 + col8, &Bs[(size_t)(256 + tid) * 8]);
        __syncthreads();

        const int kk = (lane >> 4) * 8;
        bf16x8 af[4], bfr[4];
#pragma unroll
        for (int i = 0; i < 4; ++i) {
            af[i]  = *(const bf16x8*)&As[(wr * 64 + i * 16 + (lane & 15)) * 32 + kk];
            bfr[i] = *(const bf16x8*)&Bs[(wc * 64 + i * 16 + (lane & 15)) * 32 + kk];
        }
#pragma unroll
        for (int i = 0; i < 4; ++i)
#pragma unroll
            for (int j = 0; j < 4; ++j)
                acc[i][j] = __builtin_amdgcn_mfma_f32_16x16x32_bf16(af[i], bfr[j], acc[i][j], 0, 0, 0);
        __syncthreads();
    }

#pragma unroll
    for (int i = 0; i < 4; ++i) {
        int m = bm + wr * 64 + i * 16 + (lane >> 4) * 4;
#pragma unroll
        for (int j = 0; j < 4; ++j) {
            int n = bn + wc * 64 + j * 16 + (lane & 15);
            float bv = BIAS ? bias[n] : 0.f;
#pragma unroll
            for (int r = 0; r < 4; ++r) {
                float v = acc[i][j][r] + bv;
                if (OUT_BF16)
                    ((__hip_bfloat16*)C)[(size_t)(m + r) * ldc + n] = __float2bfloat16(v);
                else if (NT)
                    __builtin_nontemporal_store(v, (float*)C + (size_t)(m + r) * ldc + n);
                else
                    ((float*)C)[(size_t)(m + r) * ldc + n] = v;
            }
        }
    }
}

// ---------------- bf16 MFMA TN GEMM, 64x64 tile (skinny N) -----------------
template<bool BIAS>
__global__ __launch_bounds__(256) void gemm64(
    const __hip_bfloat16* __restrict__ A, int lda,
    const __hip_bfloat16* __restrict__ W, int ldw,
    const float* __restrict__ bias,
    __hip_bfloat16* __restrict__ C, int ldc, int K)
{
    __shared__ __hip_bfloat16 As[64 * 32];
    __shared__ __hip_bfloat16 Bs[64 * 32];

    const int tid  = threadIdx.x;
    const int lane = tid & 63;
    const int wave = tid >> 6;
    const int wr = wave >> 1, wc = wave & 1;

    int bx = blockIdx.x, by = blockIdx.y;
    swz_rowgrp(bx, by);
    const int bm = by * 64, bn = bx * 64;

    f32x4 acc[2][2];
#pragma unroll
    for (int i = 0; i < 2; ++i)
#pragma unroll
        for (int j = 0; j < 2; ++j) acc[i][j] = f32x4{0.f, 0.f, 0.f, 0.f};

    const int srow = tid >> 2;
    const int col8 = (tid & 3) * 8;

    for (int k0 = 0; k0 < K; k0 += 32) {
        load_lds16(A + (size_t)(bm + srow) * lda + k0 + col8, &As[(size_t)tid * 8]);
        load_lds16(W + (size_t)(bn + srow) * ldw + k0 + col8, &Bs[(size_t)tid * 8]);
        __syncthreads();

        const int kk = (lane >> 4) * 8;
        bf16x8 af[2], bfr[2];
#pragma unroll
        for (int i = 0; i < 2; ++i) {
            af[i]  = *(const bf16x8*)&As[(wr * 32 + i * 16 + (lane & 15)) * 32 + kk];
            bfr[i] = *(const bf16x8*)&Bs[(wc * 32 + i * 16 + (lane & 15)) * 32 + kk];
        }
#pragma unroll
        for (int i = 0; i < 2; ++i)
#pragma unroll
            for (int j = 0; j < 2; ++j)
                acc[i][j] = __builtin_amdgcn_mfma_f32_16x16x32_bf16(af[i], bfr[j], acc[i][j], 0, 0, 0);
        __syncthreads();
    }

#pragma unroll
    for (int i = 0; i < 2; ++i) {
        int m = bm + wr * 32 + i * 16 + (lane >> 4) * 4;
#pragma unroll
        for (int j = 0; j < 2; ++j) {
            int n = bn + wc * 32 + j * 16 + (lane & 15);
            float bv = BIAS ? bias[n] : 0.f;
#pragma unroll
            for (int r = 0; r < 4; ++r)
                C[(size_t)(m + r) * ldc + n] = __float2bfloat16(acc[i][j][r] + bv);
        }
    }
}

// ---------------- xdb = ucb @ wxpad^T  (M=16384, N=48 of 64, K=512) --------
__global__ __launch_bounds__(256) void gemm_xdb(
    const __hip_bfloat16* __restrict__ A,    // ucb (MTOT,512)
    const __hip_bfloat16* __restrict__ W,    // wxpad (64,512)
    float* __restrict__ C)                   // xdb (MTOT,48)
{
    __shared__ __hip_bfloat16 As[64 * 32];
    __shared__ __hip_bfloat16 Bs[64 * 32];

    const int tid  = threadIdx.x;
    const int lane = tid & 63;
    const int wave = tid >> 6;
    const int wr = wave >> 1, wc = wave & 1;
    const int bm = blockIdx.x * 64;

    f32x4 acc[2][2];
#pragma unroll
    for (int i = 0; i < 2; ++i)
#pragma unroll
        for (int j = 0; j < 2; ++j) acc[i][j] = f32x4{0.f, 0.f, 0.f, 0.f};

    const int srow = tid >> 2;
    const int col8 = (tid & 3) * 8;

    for (int k0 = 0; k0 < DIN; k0 += 32) {
        load_lds16(A + (size_t)(bm + srow) * DIN + k0 + col8, &As[(size_t)tid * 8]);
        load_lds16(W + (size_t)srow * DIN + k0 + col8, &Bs[(size_t)tid * 8]);
        __syncthreads();

        const int kk = (lane >> 4) * 8;
        bf16x8 af[2], bfr[2];
#pragma unroll
        for (int i = 0; i < 2; ++i) {
            af[i]  = *(const bf16x8*)&As[(wr * 32 + i * 16 + (lane & 15)) * 32 + kk];
            bfr[i] = *(const bf16x8*)&Bs[(wc * 32 + i * 16 + (lane & 15)) * 32 + kk];
        }
#pragma unroll
        for (int i = 0; i < 2; ++i)
#pragma unroll
            for (int j = 0; j < 2; ++j)
                acc[i][j] = __builtin_amdgcn_mfma_f32_16x16x32_bf16(af[i], bfr[j], acc[i][j], 0, 0, 0);
        __syncthreads();
    }

#pragma unroll
    for (int i = 0; i < 2; ++i) {
        int m = bm + wr * 32 + i * 16 + (lane >> 4) * 4;
#pragma unroll
        for (int j = 0; j < 2; ++j) {
            int n = wc * 32 + j * 16 + (lane & 15);
            if (n < 48) {
#pragma unroll
                for (int r = 0; r < 4; ++r)
                    C[(size_t)(m + r) * 48 + n] = acc[i][j][r];
            }
        }
    }
}

// ---------------- conv1d + SiLU -> ucb (bf16) ------------------------------
__global__ __launch_bounds__(256) void conv_silu(
    const __hip_bfloat16* __restrict__ xz, const float* __restrict__ conv_w,
    const float* __restrict__ conv_b, __hip_bfloat16* __restrict__ ucb)
{
    int idx = blockIdx.x * 256 + threadIdx.x;   // over MTOT*DIN/8
    int d8  = (idx & 63) * 8;
    int m   = idx >> 6;
    int l   = m & (LSEQ - 1);

    float4 w4[8];
#pragma unroll
    for (int j = 0; j < 8; ++j) w4[j] = *(const float4*)(conv_w + (d8 + j) * 4);

    float acc[8];
    {
        float4 b0 = *(const float4*)(conv_b + d8);
        float4 b1 = *(const float4*)(conv_b + d8 + 4);
        acc[0]=b0.x; acc[1]=b0.y; acc[2]=b0.z; acc[3]=b0.w;
        acc[4]=b1.x; acc[5]=b1.y; acc[6]=b1.z; acc[7]=b1.w;
    }
#pragma unroll
    for (int k = 0; k < DCONV; ++k) {
        int lk = l + k - (DCONV - 1);
        if (lk >= 0) {
            bf16x8 v = *(const bf16x8*)(xz + (size_t)(m + k - (DCONV - 1)) * 1024 + d8);
#pragma unroll
            for (int j = 0; j < 8; ++j) {
                float w = (k == 0) ? w4[j].x : (k == 1) ? w4[j].y : (k == 2) ? w4[j].z : w4[j].w;
                acc[j] = fmaf(w, bf2f(v[j]), acc[j]);
            }
        }
    }

    bf16x8 ob;
#pragma unroll
    for (int j = 0; j < 8; ++j) {
        float sig = 1.f / (1.f + __expf(-acc[j]));
        float v = acc[j] * sig;
        union { __hip_bfloat16 h; short s; } cv; cv.h = __float2bfloat16(v);
        ob[j] = cv.s;
    }
    *(bf16x8*)(ucb + (size_t)m * DIN + d8) = ob;
}

// ---------------- chunked selective scan (dt fused; ucb bf16 input) ---------
__global__ __launch_bounds__(256) void scan_pass1(
    const float* __restrict__ xdb, const __hip_bfloat16* __restrict__ ucb,
    const float* __restrict__ dtw, const float* __restrict__ dtbias,
    const float* __restrict__ A_log,
    float* __restrict__ midP, float* __restrict__ midS)
{
    __shared__ float s_dt[CL][16], s_uc[CL][16], s_B[CL][16], s_xt[CL][16];
    __shared__ float s_w[16][17];
    __shared__ float s_bias[16];
    const int tid = threadIdx.x;
    const int blk = blockIdx.x;        // (b*NCH + c)*32 + dch
    const int dch = blk & 31;
    const int bc  = blk >> 5;
    const int g = tid >> 4, s = tid & 15;
    const int d = dch * 16 + g;
    const float Av = -__expf(A_log[d * DST + s]);

    {
        int row = tid >> 2, q = tid & 3;
        size_t m = (size_t)bc * CL + row;
        *(float4*)&s_B[row][q*4]  = *(const float4*)(xdb + m * 48 + 16 + q * 4);
        *(float4*)&s_xt[row][q*4] = *(const float4*)(xdb + m * 48 + q * 4);
        s_w[tid >> 4][tid & 15] = dtw[(dch * 16 + (tid >> 4)) * DTR + (tid & 15)];
        if (tid < 16) s_bias[tid] = dtbias[dch * 16 + tid];
    }
    if (tid < 128) {
        int row = tid >> 1, q = tid & 1;
        size_t m = (size_t)bc * CL + row;
        bf16x8 v = *(const bf16x8*)(ucb + m * DIN + dch * 16 + q * 8);
#pragma unroll
        for (int j = 0; j < 8; ++j) s_uc[row][q * 8 + j] = bf2f(v[j]);
    }
    __syncthreads();

#pragma unroll
    for (int p = 0; p < 4; ++p) {
        int e = p * 256 + tid;
        int tt = e >> 4, gg = e & 15;
        float a = s_bias[gg];
#pragma unroll
        for (int r = 0; r < DTR; ++r)
            a = fmaf(s_xt[tt][r], s_w[gg][r], a);
        s_dt[tt][gg] = (a > 20.f) ? a : log1pf(__expf(a));
    }
    __syncthreads();

    float h = 0.f, sdt = 0.f;
#pragma unroll 8
    for (int tt = 0; tt < CL; ++tt) {
        float dtv = s_dt[tt][g];
        float dA  = __expf(dtv * Av);
        h = fmaf(dA, h, dtv * s_uc[tt][g] * s_B[tt][s]);
        sdt += dtv;
    }
    size_t o = (size_t)blk * 256 + tid;
    midP[o] = __expf(sdt * Av);
    midS[o] = h;
}

__global__ __launch_bounds__(256) void scan_pass2(
    const float* __restrict__ midP, const float* __restrict__ midS,
    float* __restrict__ hstart)
{
    int t = blockIdx.x * 256 + threadIdx.x;
    int b  = t >> 13;
    int ds = t & 8191;
    float h = 0.f;
#pragma unroll
    for (int c = 0; c < NCH; ++c) {
        size_t o = ((size_t)(b * NCH + c) << 13) + ds;
        hstart[o] = h;
        h = fmaf(midP[o], h, midS[o]);
    }
}

__global__ __launch_bounds__(256) void scan_pass3(
    const float* __restrict__ xdb, const __hip_bfloat16* __restrict__ ucb,
    const float* __restrict__ dtw, const float* __restrict__ dtbias,
    const __hip_bfloat16* __restrict__ xz,
    const float* __restrict__ A_log, const float* __restrict__ Dp,
    const float* __restrict__ hstart, __hip_bfloat16* __restrict__ y)
{
    __shared__ float s_dt[CL][16], s_uc[CL][16], s_B[CL][16], s_C[CL][16], s_xt[CL][16], s_y[CL][16];
    __shared__ float s_w[16][17];
    __shared__ float s_bias[16];
    const int tid = threadIdx.x;
    const int blk = blockIdx.x;
    const int dch = blk & 31;
    const int bc  = blk >> 5;
    const int g = tid >> 4, s = tid & 15;
    const int d = dch * 16 + g;
    const float Av = -__expf(A_log[d * DST + s]);

    {
        int row = tid >> 2, q = tid & 3;
        size_t m = (size_t)bc * CL + row;
        *(float4*)&s_B[row][q*4]  = *(const float4*)(xdb + m * 48 + 16 + q * 4);
        *(float4*)&s_C[row][q*4]  = *(const float4*)(xdb + m * 48 + 32 + q * 4);
        *(float4*)&s_xt[row][q*4] = *(const float4*)(xdb + m * 48 + q * 4);
        s_w[tid >> 4][tid & 15] = dtw[(dch * 16 + (tid >> 4)) * DTR + (tid & 15)];
        if (tid < 16) s_bias[tid] = dtbias[dch * 16 + tid];
    }
    if (tid < 128) {
        int row = tid >> 1, q = tid & 1;
        size_t m = (size_t)bc * CL + row;
        bf16x8 v = *(const bf16x8*)(ucb + m * DIN + dch * 16 + q * 8);
#pragma unroll
        for (int j = 0; j < 8; ++j) s_uc[row][q * 8 + j] = bf2f(v[j]);
    }
    float h = hstart[(size_t)blk * 256 + tid];
    __syncthreads();

#pragma unroll
    for (int p = 0; p < 4; ++p) {
        int e = p * 256 + tid;
        int tt = e >> 4, gg = e & 15;
        float a = s_bias[gg];
#pragma unroll
        for (int r = 0; r < DTR; ++r)
            a = fmaf(s_xt[tt][r], s_w[gg][r], a);
        s_dt[tt][gg] = (a > 20.f) ? a : log1pf(__expf(a));
    }
    __syncthreads();

#pragma unroll 4
    for (int tt = 0; tt < CL; ++tt) {
        float dtv = s_dt[tt][g];
        float dA  = __expf(dtv * Av);
        h = fmaf(dA, h, dtv * s_uc[tt][g] * s_B[tt][s]);
        float p = h * s_C[tt][s];
        p += __shfl_xor(p, 1);
        p += __shfl_xor(p, 2);
        p += __shfl_xor(p, 4);
        p += __shfl_xor(p, 8);
        if (s == 0) s_y[tt][g] = p;
    }
    __syncthreads();

    for (int e = tid; e < CL * 16; e += 256) {
        int tt = e >> 4, j = e & 15;
        size_t m = (size_t)bc * CL + tt;
        int dg = dch * 16 + j;
        float zv = __bfloat162float(xz[m * 1024 + 512 + dg]);
        float sig = 1.f / (1.f + __expf(-zv));
        float val = (s_y[tt][j] + s_uc[tt][j] * Dp[dg]) * (zv * sig);
        y[m * DIN + dg] = __float2bfloat16(val);
    }
}

// ---------------- launch ----------------------------------------------------
extern "C" void kernel_launch(void* const* d_in, const int* in_sizes, int n_in,
                              void* d_out, int out_size, void* d_ws, size_t ws_size,
                              hipStream_t stream) {
    const float* x         = (const float*)d_in[0];
    const float* proj_w    = (const float*)d_in[1];
    const float* proj_b    = (const float*)d_in[2];
    const float* in_proj_w = (const float*)d_in[3];
    const float* conv_w    = (const float*)d_in[4];
    const float* conv_b    = (const float*)d_in[5];
    const float* x_proj_w  = (const float*)d_in[6];
    const float* dt_proj_w = (const float*)d_in[7];
    const float* dt_proj_b = (const float*)d_in[8];
    const float* A_log     = (const float*)d_in[9];
    const float* Dp        = (const float*)d_in[10];
    const float* out_proj_w= (const float*)d_in[11];
    const float* head_w    = (const float*)d_in[12];
    const float* head_b    = (const float*)d_in[13];
    float* out = (float*)d_out;

    // ---- workspace layout ----
    char* ws = (char*)d_ws;
    __hip_bfloat16* hbf   = (__hip_bfloat16*)ws;  ws += (size_t)MTOT * HID * 2;
    __hip_bfloat16* xzbf  = (__hip_bfloat16*)ws;  ws += (size_t)MTOT * 1024 * 2;
    __hip_bfloat16* ucb   = (__hip_bfloat16*)ws;  ws += (size_t)MTOT * DIN * 2;
    float*          xdb   = (float*)ws;           ws += (size_t)MTOT * 48 * 4;
    __hip_bfloat16* ybf   = (__hip_bfloat16*)ws;  ws += (size_t)MTOT * DIN * 2;
    __hip_bfloat16* obf   = (__hip_bfloat16*)ws;  ws += (size_t)MTOT * HID * 2;
    __hip_bfloat16* wproj = (__hip_bfloat16*)ws;  ws += (size_t)HID * STIM * 2;
    __hip_bfloat16* winp  = (__hip_bfloat16*)ws;  ws += (size_t)(2*DIN) * HID * 2;
    __hip_bfloat16* wout  = (__hip_bfloat16*)ws;  ws += (size_t)HID * DIN * 2;
    __hip_bfloat16* whead = (__hip_bfloat16*)ws;  ws += (size_t)VOX * HID * 2;
    __hip_bfloat16* wxpad = (__hip_bfloat16*)ws;  ws += (size_t)64 * DIN * 2;
    float* midP   = (float*)ws;                   ws += (size_t)BB * NCH * DIN * DST * 4;
    float* midS   = (float*)ws;                   ws += (size_t)BB * NCH * DIN * DST * 4;
    float* hstart = (float*)ws;                   ws += (size_t)BB * NCH * DIN * DST * 4;

    dim3 blk(256);

    // 0) weight conversions (one dispatch)
    cvt_weights<<<2048, blk, 0, stream>>>(proj_w, in_proj_w, out_proj_w, head_w, x_proj_w,
                                          wproj, winp, wout, whead, wxpad);

    // 1) h = x @ proj_w.T + proj_b   (fp32 A, cvt in staging; M=16384,N=256,K=1024)
    gemm_a32<<<dim3(HID / 128, MTOT / 64), blk, 0, stream>>>(
        x, STIM, wproj, STIM, proj_b, hbf, HID, STIM);

    // 2) xz = h @ in_proj_w.T        (M=16384, N=1024, K=256) -> bf16
    gemm_bf16<false, true, false><<<dim3(1024 / 128, MTOT / 128), blk, 0, stream>>>(
        hbf, HID, winp, HID, nullptr, xzbf, 1024, HID);

    // 3) ucb = silu(conv(u))
    conv_silu<<<(MTOT * DIN / 8) / 256, blk, 0, stream>>>(xzbf, conv_w, conv_b, ucb);

    // 4) xdb = ucb @ wxpad^T  (MFMA, masked n<48)
    gemm_xdb<<<MTOT / 64, blk, 0, stream>>>(ucb, wxpad, xdb);

    // 5/6) chunked selective scan with fused dt-projection + epilogue
    scan_pass1<<<BB * NCH * 32, blk, 0, stream>>>(xdb, ucb, dt_proj_w, dt_proj_b, A_log, midP, midS);
    scan_pass2<<<BB * DIN * DST / 256, blk, 0, stream>>>(midP, midS, hstart);
    scan_pass3<<<BB * NCH * 32, blk, 0, stream>>>(xdb, ucb, dt_proj_w, dt_proj_b, xzbf, A_log, Dp, hstart, ybf);

    // 7) o = y @ out_proj_w.T        (M=16384, N=256, K=512) -> bf16 (64-tile)
    gemm64<false><<<dim3(HID / 64, MTOT / 64), blk, 0, stream>>>(
        ybf, DIN, wout, DIN, nullptr, obf, HID, DIN);

    // 8) out = o @ head_w.T + head_b (M=16384, N=8192, K=256) fp32 NT stores
    gemm_bf16<true, false, true><<<dim3(VOX / 128, MTOT / 128), blk, 0, stream>>>(
        obf, HID, whead, HID, head_b, out, VOX, HID);
}